// Round 13
// baseline (411.763 us; speedup 1.0000x reference)
//
#include <hip/hip_runtime.h>
#include <hip/hip_fp16.h>
#include <math.h>

__host__ __device__ static inline int div_up(long long a, long long b) { return (int)((a + b - 1) / b); }

#define SCH 2048              // scan chunk per block (node scan)
#define NXCD 8                // XCD slices
#define PM 256                // edge chunks (one block per chunk in pcnt/partition)
#define PCM 256               // sub-blocks per slice in k_place2

typedef int int4v __attribute__((ext_vector_type(4)));

struct h8 { __half2 a, b, c, d; };   // 8 halfs = 16 B
struct h4 { __half2 a, b; };         // 4 halfs = 8 B

__device__ inline int nt_load1(const int* p) {
    return __builtin_nontemporal_load(p);
}

// ---------------- CSR build ----------------

__global__ void k_zero_i32(int* __restrict__ p, int n) {
    int i = blockIdx.x * blockDim.x + threadIdx.x;
    if (i < n) p[i] = 0;
}

// Per-chunk: node-degree atomics + per-(chunk,slice) histogram (slice-major out).
__global__ __launch_bounds__(256) void k_pcnt(const int* __restrict__ dst,
                                              int* __restrict__ cnt,
                                              int* __restrict__ pcnt, int E, int N) {
    __shared__ int h[NXCD];
    const int tid = threadIdx.x, c = blockIdx.x;
    if (tid < NXCD) h[tid] = 0;
    __syncthreads();
    const int ns = div_up(N, NXCD);
    const int ce = (div_up(E, PM) + 3) & ~3;
    const int e0 = c * ce, e1 = min(E, e0 + ce);
    for (int i = e0 + tid; i < e1; i += 256) {
        int d = dst[i];
        atomicAdd(&cnt[d], 1);
        atomicAdd(&h[d / ns], 1);
    }
    __syncthreads();
    if (tid < NXCD) pcnt[tid * PM + c] = h[tid];
}

// Node-count scan phase 1: per-block sums.
__global__ void k_scan_part(const int* __restrict__ cnt, int* __restrict__ bsum, int N) {
    __shared__ int ws[4];
    int base = blockIdx.x * SCH + threadIdx.x * 8;
    int t = 0;
#pragma unroll
    for (int j = 0; j < 8; ++j) {
        int idx = base + j;
        if (idx < N) t += cnt[idx];
    }
    for (int off = 32; off >= 1; off >>= 1) t += __shfl_xor(t, off);
    int lane = threadIdx.x & 63, wid = threadIdx.x >> 6;
    if (lane == 0) ws[wid] = t;
    __syncthreads();
    if (threadIdx.x == 0) bsum[blockIdx.x] = ws[0] + ws[1] + ws[2] + ws[3];
}

// Node-count scan phase 2 (block sums, NB <= 1024) + total -> rpN.
__global__ void k_scan_bsums(int* __restrict__ bsum, int* __restrict__ rpN, int NB) {
    __shared__ int wsum[16];
    int tid = threadIdx.x;
    int v = (tid < NB) ? bsum[tid] : 0;
    int lane = tid & 63, wid = tid >> 6;
    int x = v;
    for (int off = 1; off < 64; off <<= 1) {
        int y = __shfl_up(x, off);
        if (lane >= off) x += y;
    }
    if (lane == 63) wsum[wid] = x;
    __syncthreads();
    if (tid < 16) {
        int s = wsum[tid];
        for (int off = 1; off < 16; off <<= 1) {
            int y = __shfl_up(s, off);
            if (tid >= off) s += y;
        }
        wsum[tid] = s;
    }
    __syncthreads();
    int woff = (wid > 0) ? wsum[wid - 1] : 0;
    int excl = woff + x - v;
    if (tid < NB) bsum[tid] = excl;
    if (tid == NB - 1) rpN[0] = excl + v;
}

// Node-count scan phase 3: emits rp, cur, dis.
__global__ void k_scan_apply(const int* __restrict__ cnt, const int* __restrict__ bsum,
                             int* __restrict__ rp, int* __restrict__ cur,
                             float* __restrict__ dis, int N) {
    __shared__ int wsum[4];
    int tid = threadIdx.x;
    int base = blockIdx.x * SCH + tid * 8;
    int v[8];
    int t = 0;
#pragma unroll
    for (int j = 0; j < 8; ++j) {
        int idx = base + j;
        v[j] = (idx < N) ? cnt[idx] : 0;
        t += v[j];
    }
    int lane = tid & 63, wid = tid >> 6;
    int x = t;
    for (int off = 1; off < 64; off <<= 1) {
        int y = __shfl_up(x, off);
        if (lane >= off) x += y;
    }
    if (lane == 63) wsum[wid] = x;
    __syncthreads();
    int woff = 0;
    for (int w = 0; w < wid; ++w) woff += wsum[w];
    int run = bsum[blockIdx.x] + woff + (x - t);
#pragma unroll
    for (int j = 0; j < 8; ++j) {
        int idx = base + j;
        if (idx < N) {
            rp[idx] = run;
            cur[idx] = run;
            dis[idx] = rsqrtf((float)v[j] + 1.0f);
        }
        run += v[j];
    }
}

// Exclusive scan of pcnt (2048 = PM*NXCD values, slice-major) -> pbase, +total at [2048].
__global__ void k_scan2048(const int* __restrict__ pcnt, int* __restrict__ pbase) {
    __shared__ int wsum[4];
    int tid = threadIdx.x;
    int base = tid * 8;
    int v[8];
    int t = 0;
#pragma unroll
    for (int j = 0; j < 8; ++j) { v[j] = pcnt[base + j]; t += v[j]; }
    int lane = tid & 63, wid = tid >> 6;
    int x = t;
    for (int off = 1; off < 64; off <<= 1) {
        int y = __shfl_up(x, off);
        if (lane >= off) x += y;
    }
    if (lane == 63) wsum[wid] = x;
    __syncthreads();
    int woff = 0;
    for (int w = 0; w < wid; ++w) woff += wsum[w];
    int run = woff + (x - t);
#pragma unroll
    for (int j = 0; j < 8; ++j) { pbase[base + j] = run; run += v[j]; }
    if (tid == 255) pbase[PM * NXCD] = run;   // = E
}

// Partition edges into per-(slice,chunk) pair regions. LDS cursors -> writes are
// time-dense (a 64B line fills within ~1 wave iter) => ~1x write amplification.
__global__ __launch_bounds__(256) void k_partition(
        const int* __restrict__ src, const int* __restrict__ dst,
        const int* __restrict__ pbase, uint2* __restrict__ pairs, int E, int N) {
    __shared__ int base8[NXCD];
    __shared__ int lc[NXCD];
    const int tid = threadIdx.x, c = blockIdx.x;
    if (tid < NXCD) { base8[tid] = pbase[tid * PM + c]; lc[tid] = 0; }
    __syncthreads();
    const int ns = div_up(N, NXCD);
    const int ce = (div_up(E, PM) + 3) & ~3;
    const int e0 = c * ce, e1 = min(E, e0 + ce);
    for (int i = e0 + tid; i < e1; i += 256) {
        int d = dst[i], s = src[i];
        int sl = d / ns;
        int idx = atomicAdd(&lc[sl], 1);
        pairs[base8[sl] + idx] = make_uint2((unsigned)s, (unsigned)d);
    }
}

// Place: slice = bid % NXCD (XCD-owned). Per-slice working set (1.6MB pairs
// stream + 0.8MB csrc dirty + cur) fits the XCD's 4MB L2 -> dense writes.
__global__ __launch_bounds__(256) void k_place2(
        const uint2* __restrict__ pairs, const int* __restrict__ pbase,
        int* __restrict__ cur, int* __restrict__ csrc) {
    const int slice = blockIdx.x % NXCD;
    const int m = blockIdx.x / NXCD;
    const int p0 = pbase[slice * PM];
    const int p1 = pbase[(slice + 1) * PM];
    const int cntS = p1 - p0;
    const int per = div_up(cntS, PCM);
    const int q0 = p0 + m * per;
    const int q1 = min(p1, q0 + per);
    for (int i = q0 + threadIdx.x; i < q1; i += 256) {
        uint2 pr = pairs[i];
        csrc[atomicAdd(&cur[pr.y], 1)] = (int)pr.x;
    }
}

// ---------------- propagation (fp16 rows, fp32 accumulate) ----------------

__device__ inline void fma_h8(float* acc, float w, const h8& v) {
    float2 f0 = __half22float2(v.a), f1 = __half22float2(v.b);
    float2 f2 = __half22float2(v.c), f3 = __half22float2(v.d);
    acc[0] += w * f0.x; acc[1] += w * f0.y;
    acc[2] += w * f1.x; acc[3] += w * f1.y;
    acc[4] += w * f2.x; acc[5] += w * f2.y;
    acc[6] += w * f3.x; acc[7] += w * f3.y;
}

template<int F>  // F in halfs per row; TPE = F/8
__global__ __launch_bounds__(256) void k_prop_h(
        const int* __restrict__ rp, const int* __restrict__ csrc,
        const float* __restrict__ dis,
        const __half* __restrict__ hin, __half* __restrict__ hout, int N) {
    constexpr int TPE = F / 8;
    int t = blockIdx.x * blockDim.x + threadIdx.x;
    int n = t / TPE;
    if (n >= N) return;
    int l = t % TPE;
    float dn = dis[n];
    float acc[8];
    {
        h8 v = *reinterpret_cast<const h8*>(hin + (size_t)n * F + 8 * l);
        float wn = dn * dn;
#pragma unroll
        for (int j = 0; j < 8; ++j) acc[j] = 0.f;
        fma_h8(acc, wn, v);
    }
    int e = rp[n], end = rp[n + 1];
    for (; e + 7 < end; e += 8) {
        int s[8];
        float w[8];
        h8 v[8];
#pragma unroll
        for (int j = 0; j < 8; ++j) s[j] = nt_load1(csrc + e + j);
#pragma unroll
        for (int j = 0; j < 8; ++j) w[j] = dis[s[j]] * dn;
#pragma unroll
        for (int j = 0; j < 8; ++j)
            v[j] = *reinterpret_cast<const h8*>(hin + (size_t)s[j] * F + 8 * l);
#pragma unroll
        for (int j = 0; j < 8; ++j) fma_h8(acc, w[j], v[j]);
    }
    for (; e < end; ++e) {
        int s = nt_load1(csrc + e);
        float w = dis[s] * dn;
        h8 v = *reinterpret_cast<const h8*>(hin + (size_t)s * F + 8 * l);
        fma_h8(acc, w, v);
    }
    h8 o;
    o.a = __float22half2_rn(make_float2(acc[0], acc[1]));
    o.b = __float22half2_rn(make_float2(acc[2], acc[3]));
    o.c = __float22half2_rn(make_float2(acc[4], acc[5]));
    o.d = __float22half2_rn(make_float2(acc[6], acc[7]));
    *reinterpret_cast<h8*>(hout + (size_t)n * F + 8 * l) = o;
}

// ---------------- dense layers (register-tiled) ----------------

#define FMA4(a, s, v) { (a).x += (s) * (v).x; (a).y += (s) * (v).y; \
                        (a).z += (s) * (v).z; (a).w += (s) * (v).w; }

// Y[n,h] = X[n,:128] @ W[:,h], output fp16. Tile: 64 nodes x 64 h, 4x4/thread.
__global__ __launch_bounds__(256) void k_gemm1(const float* __restrict__ X,
                                               const float* __restrict__ W,
                                               __half* __restrict__ Y, int N) {
    __shared__ float sx[64][132];
    __shared__ float sw[128][68];
    const int tid = threadIdx.x;
    const int n0 = blockIdx.x * 64;
    const bool full = (n0 + 64 <= N);
#pragma unroll
    for (int j = 0; j < 8; ++j) {
        int idx = (tid + j * 256) * 4;
        int k = idx >> 6, h = idx & 63;
        *reinterpret_cast<float4*>(&sw[k][h]) = *reinterpret_cast<const float4*>(W + idx);
    }
#pragma unroll
    for (int j = 0; j < 8; ++j) {
        int idx = (tid + j * 256) * 4;
        int n = idx >> 7, k = idx & 127;
        float4 v = make_float4(0.f, 0.f, 0.f, 0.f);
        if (full || n0 + n < N)
            v = *reinterpret_cast<const float4*>(X + (size_t)(n0 + n) * 128 + k);
        *reinterpret_cast<float4*>(&sx[n][k]) = v;
    }
    __syncthreads();
    const int lane = tid & 63, wid = tid >> 6;
    const int h0 = (lane & 15) * 4;
    const int nb = wid * 16 + (lane >> 4) * 4;
    float4 a0 = {0,0,0,0}, a1 = {0,0,0,0}, a2 = {0,0,0,0}, a3 = {0,0,0,0};
#pragma unroll 4
    for (int k0 = 0; k0 < 128; k0 += 4) {
        float4 x0 = *reinterpret_cast<float4*>(&sx[nb + 0][k0]);
        float4 x1 = *reinterpret_cast<float4*>(&sx[nb + 1][k0]);
        float4 x2 = *reinterpret_cast<float4*>(&sx[nb + 2][k0]);
        float4 x3 = *reinterpret_cast<float4*>(&sx[nb + 3][k0]);
        float4 w0 = *reinterpret_cast<float4*>(&sw[k0 + 0][h0]);
        float4 w1 = *reinterpret_cast<float4*>(&sw[k0 + 1][h0]);
        float4 w2 = *reinterpret_cast<float4*>(&sw[k0 + 2][h0]);
        float4 w3 = *reinterpret_cast<float4*>(&sw[k0 + 3][h0]);
        FMA4(a0, x0.x, w0); FMA4(a0, x0.y, w1); FMA4(a0, x0.z, w2); FMA4(a0, x0.w, w3);
        FMA4(a1, x1.x, w0); FMA4(a1, x1.y, w1); FMA4(a1, x1.z, w2); FMA4(a1, x1.w, w3);
        FMA4(a2, x2.x, w0); FMA4(a2, x2.y, w1); FMA4(a2, x2.z, w2); FMA4(a2, x2.w, w3);
        FMA4(a3, x3.x, w0); FMA4(a3, x3.y, w1); FMA4(a3, x3.z, w2); FMA4(a3, x3.w, w3);
    }
    int n = n0 + nb;
#pragma unroll
    for (int r = 0; r < 4; ++r) {
        float4 a = (r == 0) ? a0 : (r == 1) ? a1 : (r == 2) ? a2 : a3;
        if (n + r < N) {
            h4 o;
            o.a = __float22half2_rn(make_float2(a.x, a.y));
            o.b = __float22half2_rn(make_float2(a.z, a.w));
            *reinterpret_cast<h4*>(Y + (size_t)(n + r) * 64 + h0) = o;
        }
    }
}

// T[n,c] = relu(H[n,:64]+b1) @ W2[:,c]; H fp16 in, T fp16 out (c<40, padded 64).
__global__ __launch_bounds__(256) void k_gemm2(const __half* __restrict__ H,
                                               const float* __restrict__ b1,
                                               const float* __restrict__ W2,
                                               __half* __restrict__ T, int N) {
    __shared__ float sh[64][68];
    __shared__ float sw[64][68];
    const int tid = threadIdx.x;
    const int n0 = blockIdx.x * 64;
    const bool full = (n0 + 64 <= N);
#pragma unroll
    for (int j = 0; j < 4; ++j) {
        int idx = (tid + j * 256) * 4;
        int k = idx >> 6, h = idx & 63;
        float4 v = make_float4(0.f, 0.f, 0.f, 0.f);
        if (h < 40) v = *reinterpret_cast<const float4*>(W2 + k * 40 + h);
        *reinterpret_cast<float4*>(&sw[k][h]) = v;
    }
#pragma unroll
    for (int j = 0; j < 2; ++j) {
        int idx = (tid + j * 256) * 8;
        int n = idx >> 6, k = idx & 63;
        float v[8];
        if (full || n0 + n < N) {
            h8 hv = *reinterpret_cast<const h8*>(H + (size_t)(n0 + n) * 64 + k);
            float2 f0 = __half22float2(hv.a), f1 = __half22float2(hv.b);
            float2 f2 = __half22float2(hv.c), f3 = __half22float2(hv.d);
            v[0] = f0.x; v[1] = f0.y; v[2] = f1.x; v[3] = f1.y;
            v[4] = f2.x; v[5] = f2.y; v[6] = f3.x; v[7] = f3.y;
#pragma unroll
            for (int q = 0; q < 8; ++q) v[q] = fmaxf(v[q] + b1[k + q], 0.f);
        } else {
#pragma unroll
            for (int q = 0; q < 8; ++q) v[q] = 0.f;
        }
#pragma unroll
        for (int q = 0; q < 8; ++q) sh[n][k + q] = v[q];
    }
    __syncthreads();
    const int lane = tid & 63, wid = tid >> 6;
    const int h0 = (lane & 15) * 4;
    const int nb = wid * 16 + (lane >> 4) * 4;
    float4 a0 = {0,0,0,0}, a1 = {0,0,0,0}, a2 = {0,0,0,0}, a3 = {0,0,0,0};
#pragma unroll 4
    for (int k0 = 0; k0 < 64; k0 += 4) {
        float4 x0 = *reinterpret_cast<float4*>(&sh[nb + 0][k0]);
        float4 x1 = *reinterpret_cast<float4*>(&sh[nb + 1][k0]);
        float4 x2 = *reinterpret_cast<float4*>(&sh[nb + 2][k0]);
        float4 x3 = *reinterpret_cast<float4*>(&sh[nb + 3][k0]);
        float4 w0 = *reinterpret_cast<float4*>(&sw[k0 + 0][h0]);
        float4 w1 = *reinterpret_cast<float4*>(&sw[k0 + 1][h0]);
        float4 w2 = *reinterpret_cast<float4*>(&sw[k0 + 2][h0]);
        float4 w3 = *reinterpret_cast<float4*>(&sw[k0 + 3][h0]);
        FMA4(a0, x0.x, w0); FMA4(a0, x0.y, w1); FMA4(a0, x0.z, w2); FMA4(a0, x0.w, w3);
        FMA4(a1, x1.x, w0); FMA4(a1, x1.y, w1); FMA4(a1, x1.z, w2); FMA4(a1, x1.w, w3);
        FMA4(a2, x2.x, w0); FMA4(a2, x2.y, w1); FMA4(a2, x2.z, w2); FMA4(a2, x2.w, w3);
        FMA4(a3, x3.x, w0); FMA4(a3, x3.y, w1); FMA4(a3, x3.z, w2); FMA4(a3, x3.w, w3);
    }
    if (h0 < 40) {
        int n = n0 + nb;
#pragma unroll
        for (int r = 0; r < 4; ++r) {
            float4 a = (r == 0) ? a0 : (r == 1) ? a1 : (r == 2) ? a2 : a3;
            if (n + r < N) {
                h4 o;
                o.a = __float22half2_rn(make_float2(a.x, a.y));
                o.b = __float22half2_rn(make_float2(a.z, a.w));
                *reinterpret_cast<h4*>(T + (size_t)(n + r) * 40 + h0) = o;
            }
        }
    }
}

// out[n,c] = log_softmax(T[n,:40] + b2), T fp16. One wave per node.
__global__ void k_bias_lsm(const __half* __restrict__ T, const float* __restrict__ b2,
                           float* __restrict__ Y, int N) {
    int gid = blockIdx.x * blockDim.x + threadIdx.x;
    int node = gid >> 6;
    int lane = threadIdx.x & 63;
    if (node >= N) return;
    float v = (lane < 40) ? __half2float(T[(size_t)node * 40 + lane]) + b2[lane] : -INFINITY;
    float m = v;
    for (int off = 32; off >= 1; off >>= 1) m = fmaxf(m, __shfl_xor(m, off));
    float ev = (lane < 40) ? expf(v - m) : 0.0f;
    float s = ev;
    for (int off = 32; off >= 1; off >>= 1) s += __shfl_xor(s, off);
    if (lane < 40) Y[(size_t)node * 40 + lane] = v - m - logf(s);
}

// ---------------- launch ----------------

extern "C" void kernel_launch(void* const* d_in, const int* in_sizes, int n_in,
                              void* d_out, int out_size, void* d_ws, size_t ws_size,
                              hipStream_t stream) {
    const float* x  = (const float*)d_in[0];
    const int*   ei = (const int*)d_in[1];
    const float* W1 = (const float*)d_in[2];
    const float* b1 = (const float*)d_in[3];
    const float* W2 = (const float*)d_in[4];
    const float* b2 = (const float*)d_in[5];
    float* out = (float*)d_out;

    const int H = in_sizes[3];            // 64
    const int F = in_sizes[2] / H;        // 128
    const int N = in_sizes[0] / F;        // 100000
    const int E = in_sizes[1] / 2;        // 1600000
    (void)ws_size; (void)n_in; (void)out_size;

    const int* src = ei;
    const int* dst = ei + E;
    const int NSB = div_up(N, SCH);       // node-scan blocks (49)

    // workspace layout
    const int Npad = (N + 256) & ~255;          // covers N+1
    float* dis  = (float*)d_ws;                 // N
    int*   cnt  = (int*)(dis + Npad);           // N
    int*   rp   = cnt + Npad;                   // N+1
    int*   cur  = rp + Npad;                    // N
    int*   bsum = cur + Npad;                   // NSB
    int*   pcnt = bsum + ((NSB + 255) & ~255);  // PM*NXCD = 2048
    int*   pbase = pcnt + 2048;                 // 2049 (padded to 2304)
    int*   csrc = pbase + 2304;                 // E
    __half* bufA = (__half*)(csrc + ((E + 255) & ~255));   // N*64 halfs
    __half* bufB = bufA + (size_t)N * 64;                  // N*64 halfs
    uint2* pairs = (uint2*)bufB;                // E pairs = 12.8MB, dead until prop1

    const int B = 256;

    // ---- CSR build ----
    k_zero_i32<<<div_up(N, B), B, 0, stream>>>(cnt, N);
    k_pcnt<<<PM, 256, 0, stream>>>(dst, cnt, pcnt, E, N);
    k_scan_part<<<NSB, 256, 0, stream>>>(cnt, bsum, N);
    k_scan_bsums<<<1, 1024, 0, stream>>>(bsum, rp + N, NSB);
    k_scan_apply<<<NSB, 256, 0, stream>>>(cnt, bsum, rp, cur, dis, N);
    k_scan2048<<<1, 256, 0, stream>>>(pcnt, pbase);
    k_partition<<<PM, 256, 0, stream>>>(src, dst, pbase, pairs, E, N);
    k_place2<<<NXCD * PCM, 256, 0, stream>>>(pairs, pbase, cur, csrc);

    // ---- layer 1 (commuted): Y0 = X @ W1 (fp16), then 2 props at F=64 ----
    k_gemm1<<<div_up(N, 64), 256, 0, stream>>>(x, W1, bufA, N);
    k_prop_h<64><<<div_up((long long)N * 8, B), B, 0, stream>>>(rp, csrc, dis, bufA, bufB, N);
    k_prop_h<64><<<div_up((long long)N * 8, B), B, 0, stream>>>(rp, csrc, dis, bufB, bufA, N);

    // ---- layer 2 (commuted): T = relu(h + b1) @ W2 (fp16), then 2 props at F=40 ----
    k_gemm2<<<div_up(N, 64), 256, 0, stream>>>(bufA, b1, W2, bufB, N);
    k_prop_h<40><<<div_up((long long)N * 5, B), B, 0, stream>>>(rp, csrc, dis, bufB, bufA, N);
    k_prop_h<40><<<div_up((long long)N * 5, B), B, 0, stream>>>(rp, csrc, dis, bufA, bufB, N);

    // ---- epilogue: out = log_softmax(T + b2) ----
    k_bias_lsm<<<div_up((long long)N * 64, 256), 256, 0, stream>>>(bufB, b2, out, N);
}

// Round 14
// 368.078 us; speedup vs baseline: 1.1187x; 1.1187x over previous
//
#include <hip/hip_runtime.h>
#include <hip/hip_fp16.h>
#include <math.h>

__host__ __device__ static inline int div_up(long long a, long long b) { return (int)((a + b - 1) / b); }

#define SCH 2048              // scan chunk per block
#define PM 256                // edge chunks (one block per chunk in histA/partitionA)
#define BKN 256               // nodes per bucket (shift 8)
#define CAP 8192              // LDS staging capacity (edges) in k_placeB

typedef int int4v __attribute__((ext_vector_type(4)));

struct h8 { __half2 a, b, c, d; };   // 8 halfs = 16 B
struct h4 { __half2 a, b; };         // 4 halfs = 8 B

__device__ inline int4v nt_load4(const int* p) {
    return __builtin_nontemporal_load(reinterpret_cast<const int4v*>(p));
}
__device__ inline int nt_load1(const int* p) {
    return __builtin_nontemporal_load(p);
}

// ---------------- CSR build ----------------

__global__ void k_zero_i32(int* __restrict__ p, int n) {
    int i = blockIdx.x * blockDim.x + threadIdx.x;
    if (i < n) p[i] = 0;
}

// One pass over dst: per-node degree atomics (no return -> cheap) + LDS
// histogram over NBK node-buckets; out slice-major histA[b*PM + c].
__global__ __launch_bounds__(256) void k_histA(const int* __restrict__ dst,
                                               int* __restrict__ cnt,
                                               int* __restrict__ histA,
                                               int E, int NBK) {
    __shared__ int h[1024];               // NBK <= 1024 (N <= 262144)
    const int tid = threadIdx.x, c = blockIdx.x;
    for (int i = tid; i < NBK; i += 256) h[i] = 0;
    __syncthreads();
    const int ce = (div_up(E, PM) + 3) & ~3;
    const int e0 = c * ce, e1 = min(E, e0 + ce);
    int i = e0 + tid * 4;
    for (; i + 3 < e1; i += 256 * 4) {
        int4v d = nt_load4(dst + i);
        atomicAdd(&cnt[d.x], 1); atomicAdd(&h[d.x >> 8], 1);
        atomicAdd(&cnt[d.y], 1); atomicAdd(&h[d.y >> 8], 1);
        atomicAdd(&cnt[d.z], 1); atomicAdd(&h[d.z >> 8], 1);
        atomicAdd(&cnt[d.w], 1); atomicAdd(&h[d.w >> 8], 1);
    }
    for (int j = i; j < e1; ++j) {
        int d = dst[j];
        atomicAdd(&cnt[d], 1); atomicAdd(&h[d >> 8], 1);
    }
    __syncthreads();
    for (int b = tid; b < NBK; b += 256) histA[b * PM + c] = h[b];
}

// Scan phase 1: per-block sums of SCH-element chunks (generic length).
__global__ void k_scan_part(const int* __restrict__ a, int* __restrict__ bsum, int len) {
    __shared__ int ws[4];
    int base = blockIdx.x * SCH + threadIdx.x * 8;
    int t = 0;
#pragma unroll
    for (int j = 0; j < 8; ++j) {
        int idx = base + j;
        if (idx < len) t += a[idx];
    }
    for (int off = 32; off >= 1; off >>= 1) t += __shfl_xor(t, off);
    int lane = threadIdx.x & 63, wid = threadIdx.x >> 6;
    if (lane == 0) ws[wid] = t;
    __syncthreads();
    if (threadIdx.x == 0) bsum[blockIdx.x] = ws[0] + ws[1] + ws[2] + ws[3];
}

// Scan phase 2 (block sums, NB <= 1024) + grand total -> tot[0].
__global__ void k_scan_bsums(int* __restrict__ bsum, int* __restrict__ tot, int NB) {
    __shared__ int wsum[16];
    int tid = threadIdx.x;
    int v = (tid < NB) ? bsum[tid] : 0;
    int lane = tid & 63, wid = tid >> 6;
    int x = v;
    for (int off = 1; off < 64; off <<= 1) {
        int y = __shfl_up(x, off);
        if (lane >= off) x += y;
    }
    if (lane == 63) wsum[wid] = x;
    __syncthreads();
    if (tid < 16) {
        int s = wsum[tid];
        for (int off = 1; off < 16; off <<= 1) {
            int y = __shfl_up(s, off);
            if (tid >= off) s += y;
        }
        wsum[tid] = s;
    }
    __syncthreads();
    int woff = (wid > 0) ? wsum[wid - 1] : 0;
    int excl = woff + x - v;
    if (tid < NB) bsum[tid] = excl;
    if (tid == NB - 1) tot[0] = excl + v;
}

// Scan phase 3 (node variant): emits rp, cur, dis.
__global__ void k_scan_apply(const int* __restrict__ cnt, const int* __restrict__ bsum,
                             int* __restrict__ rp, int* __restrict__ cur,
                             float* __restrict__ dis, int N) {
    __shared__ int wsum[4];
    int tid = threadIdx.x;
    int base = blockIdx.x * SCH + tid * 8;
    int v[8];
    int t = 0;
#pragma unroll
    for (int j = 0; j < 8; ++j) {
        int idx = base + j;
        v[j] = (idx < N) ? cnt[idx] : 0;
        t += v[j];
    }
    int lane = tid & 63, wid = tid >> 6;
    int x = t;
    for (int off = 1; off < 64; off <<= 1) {
        int y = __shfl_up(x, off);
        if (lane >= off) x += y;
    }
    if (lane == 63) wsum[wid] = x;
    __syncthreads();
    int woff = 0;
    for (int w = 0; w < wid; ++w) woff += wsum[w];
    int run = bsum[blockIdx.x] + woff + (x - t);
#pragma unroll
    for (int j = 0; j < 8; ++j) {
        int idx = base + j;
        if (idx < N) {
            rp[idx] = run;
            cur[idx] = run;
            dis[idx] = rsqrtf((float)v[j] + 1.0f);
        }
        run += v[j];
    }
}

// Scan phase 3 (plain, in-place): a <- exclusive_scan(a).
__global__ void k_scan_apply_plain(int* __restrict__ a, const int* __restrict__ bsum,
                                   int len) {
    __shared__ int wsum[4];
    int tid = threadIdx.x;
    int base = blockIdx.x * SCH + tid * 8;
    int v[8];
    int t = 0;
#pragma unroll
    for (int j = 0; j < 8; ++j) {
        int idx = base + j;
        v[j] = (idx < len) ? a[idx] : 0;
        t += v[j];
    }
    int lane = tid & 63, wid = tid >> 6;
    int x = t;
    for (int off = 1; off < 64; off <<= 1) {
        int y = __shfl_up(x, off);
        if (lane >= off) x += y;
    }
    if (lane == 63) wsum[wid] = x;
    __syncthreads();
    int woff = 0;
    for (int w = 0; w < wid; ++w) woff += wsum[w];
    int run = bsum[blockIdx.x] + woff + (x - t);
#pragma unroll
    for (int j = 0; j < 8; ++j) {
        int idx = base + j;
        if (idx < len) a[idx] = run;
        run += v[j];
    }
}

// Partition edges into per-(bucket,chunk) pair regions via LDS cursors
// (zero global atomics; ~16 pairs per open stream -> dense line fills).
__global__ __launch_bounds__(256) void k_partitionA(
        const int* __restrict__ src, const int* __restrict__ dst,
        const int* __restrict__ pbase, uint2* __restrict__ pairs, int E, int NBK) {
    __shared__ int curb[1024];
    const int tid = threadIdx.x, c = blockIdx.x;
    for (int b = tid; b < NBK; b += 256) curb[b] = pbase[b * PM + c];
    __syncthreads();
    const int ce = (div_up(E, PM) + 3) & ~3;
    const int e0 = c * ce, e1 = min(E, e0 + ce);
    int i = e0 + tid * 4;
    for (; i + 3 < e1; i += 256 * 4) {
        int4v d4 = nt_load4(dst + i);
        int4v s4 = nt_load4(src + i);
        int p0 = atomicAdd(&curb[d4.x >> 8], 1); pairs[p0] = make_uint2((unsigned)s4.x, (unsigned)d4.x);
        int p1 = atomicAdd(&curb[d4.y >> 8], 1); pairs[p1] = make_uint2((unsigned)s4.y, (unsigned)d4.y);
        int p2 = atomicAdd(&curb[d4.z >> 8], 1); pairs[p2] = make_uint2((unsigned)s4.z, (unsigned)d4.z);
        int p3 = atomicAdd(&curb[d4.w >> 8], 1); pairs[p3] = make_uint2((unsigned)s4.w, (unsigned)d4.w);
    }
    for (int j = i; j < e1; ++j) {
        int d = dst[j];
        int p = atomicAdd(&curb[d >> 8], 1);
        pairs[p] = make_uint2((unsigned)src[j], (unsigned)d);
    }
}

// Final place: one block per bucket. Bucket b's pairs live at [rp[256b], rp[256(b+1)])
// (bucket-major scan == rp at bucket boundaries). LDS counting-sort -> coalesced
// csrc writes. Fallback to global atomics only on (improbable) LDS overflow.
__global__ __launch_bounds__(256) void k_placeB(
        const uint2* __restrict__ pairs, const int* __restrict__ rp,
        int* __restrict__ cur, int* __restrict__ csrc, int N) {
    __shared__ int curl[BKN];
    __shared__ int stage[CAP];
    const int b = blockIdx.x;
    const int n0 = b * BKN;
    const int n1 = min(N, n0 + BKN);
    const int base = rp[n0], end = rp[n1];
    const int cntb = end - base;
    const int tid = threadIdx.x;
    if (cntb <= CAP) {
        if (n0 + tid < n1) curl[tid] = rp[n0 + tid] - base;
        __syncthreads();
        for (int i = base + tid; i < end; i += 256) {
            uint2 pr = pairs[i];
            int p = atomicAdd(&curl[pr.y - n0], 1);
            stage[p] = (int)pr.x;
        }
        __syncthreads();
        for (int i = tid; i < cntb; i += 256) csrc[base + i] = stage[i];
    } else {
        for (int i = base + tid; i < end; i += 256) {
            uint2 pr = pairs[i];
            csrc[atomicAdd(&cur[pr.y], 1)] = (int)pr.x;
        }
    }
}

// ---------------- propagation (fp16 rows, fp32 accumulate) ----------------

__device__ inline void fma_h8(float* acc, float w, const h8& v) {
    float2 f0 = __half22float2(v.a), f1 = __half22float2(v.b);
    float2 f2 = __half22float2(v.c), f3 = __half22float2(v.d);
    acc[0] += w * f0.x; acc[1] += w * f0.y;
    acc[2] += w * f1.x; acc[3] += w * f1.y;
    acc[4] += w * f2.x; acc[5] += w * f2.y;
    acc[6] += w * f3.x; acc[7] += w * f3.y;
}

template<int F>  // F in halfs per row; TPE = F/8
__global__ __launch_bounds__(256) void k_prop_h(
        const int* __restrict__ rp, const int* __restrict__ csrc,
        const float* __restrict__ dis,
        const __half* __restrict__ hin, __half* __restrict__ hout, int N) {
    constexpr int TPE = F / 8;
    int t = blockIdx.x * blockDim.x + threadIdx.x;
    int n = t / TPE;
    if (n >= N) return;
    int l = t % TPE;
    float dn = dis[n];
    float acc[8];
    {
        h8 v = *reinterpret_cast<const h8*>(hin + (size_t)n * F + 8 * l);
        float wn = dn * dn;
#pragma unroll
        for (int j = 0; j < 8; ++j) acc[j] = 0.f;
        fma_h8(acc, wn, v);
    }
    int e = rp[n], end = rp[n + 1];
    for (; e + 7 < end; e += 8) {
        int s[8];
        float w[8];
        h8 v[8];
#pragma unroll
        for (int j = 0; j < 8; ++j) s[j] = nt_load1(csrc + e + j);
#pragma unroll
        for (int j = 0; j < 8; ++j) w[j] = dis[s[j]] * dn;
#pragma unroll
        for (int j = 0; j < 8; ++j)
            v[j] = *reinterpret_cast<const h8*>(hin + (size_t)s[j] * F + 8 * l);
#pragma unroll
        for (int j = 0; j < 8; ++j) fma_h8(acc, w[j], v[j]);
    }
    for (; e < end; ++e) {
        int s = nt_load1(csrc + e);
        float w = dis[s] * dn;
        h8 v = *reinterpret_cast<const h8*>(hin + (size_t)s * F + 8 * l);
        fma_h8(acc, w, v);
    }
    h8 o;
    o.a = __float22half2_rn(make_float2(acc[0], acc[1]));
    o.b = __float22half2_rn(make_float2(acc[2], acc[3]));
    o.c = __float22half2_rn(make_float2(acc[4], acc[5]));
    o.d = __float22half2_rn(make_float2(acc[6], acc[7]));
    *reinterpret_cast<h8*>(hout + (size_t)n * F + 8 * l) = o;
}

// ---------------- dense layers (register-tiled) ----------------

#define FMA4(a, s, v) { (a).x += (s) * (v).x; (a).y += (s) * (v).y; \
                        (a).z += (s) * (v).z; (a).w += (s) * (v).w; }

// Y[n,h] = X[n,:128] @ W[:,h], output fp16. Tile: 64 nodes x 64 h, 4x4/thread.
__global__ __launch_bounds__(256) void k_gemm1(const float* __restrict__ X,
                                               const float* __restrict__ W,
                                               __half* __restrict__ Y, int N) {
    __shared__ float sx[64][132];
    __shared__ float sw[128][68];
    const int tid = threadIdx.x;
    const int n0 = blockIdx.x * 64;
    const bool full = (n0 + 64 <= N);
#pragma unroll
    for (int j = 0; j < 8; ++j) {
        int idx = (tid + j * 256) * 4;
        int k = idx >> 6, h = idx & 63;
        *reinterpret_cast<float4*>(&sw[k][h]) = *reinterpret_cast<const float4*>(W + idx);
    }
#pragma unroll
    for (int j = 0; j < 8; ++j) {
        int idx = (tid + j * 256) * 4;
        int n = idx >> 7, k = idx & 127;
        float4 v = make_float4(0.f, 0.f, 0.f, 0.f);
        if (full || n0 + n < N)
            v = *reinterpret_cast<const float4*>(X + (size_t)(n0 + n) * 128 + k);
        *reinterpret_cast<float4*>(&sx[n][k]) = v;
    }
    __syncthreads();
    const int lane = tid & 63, wid = tid >> 6;
    const int h0 = (lane & 15) * 4;
    const int nb = wid * 16 + (lane >> 4) * 4;
    float4 a0 = {0,0,0,0}, a1 = {0,0,0,0}, a2 = {0,0,0,0}, a3 = {0,0,0,0};
#pragma unroll 4
    for (int k0 = 0; k0 < 128; k0 += 4) {
        float4 x0 = *reinterpret_cast<float4*>(&sx[nb + 0][k0]);
        float4 x1 = *reinterpret_cast<float4*>(&sx[nb + 1][k0]);
        float4 x2 = *reinterpret_cast<float4*>(&sx[nb + 2][k0]);
        float4 x3 = *reinterpret_cast<float4*>(&sx[nb + 3][k0]);
        float4 w0 = *reinterpret_cast<float4*>(&sw[k0 + 0][h0]);
        float4 w1 = *reinterpret_cast<float4*>(&sw[k0 + 1][h0]);
        float4 w2 = *reinterpret_cast<float4*>(&sw[k0 + 2][h0]);
        float4 w3 = *reinterpret_cast<float4*>(&sw[k0 + 3][h0]);
        FMA4(a0, x0.x, w0); FMA4(a0, x0.y, w1); FMA4(a0, x0.z, w2); FMA4(a0, x0.w, w3);
        FMA4(a1, x1.x, w0); FMA4(a1, x1.y, w1); FMA4(a1, x1.z, w2); FMA4(a1, x1.w, w3);
        FMA4(a2, x2.x, w0); FMA4(a2, x2.y, w1); FMA4(a2, x2.z, w2); FMA4(a2, x2.w, w3);
        FMA4(a3, x3.x, w0); FMA4(a3, x3.y, w1); FMA4(a3, x3.z, w2); FMA4(a3, x3.w, w3);
    }
    int n = n0 + nb;
#pragma unroll
    for (int r = 0; r < 4; ++r) {
        float4 a = (r == 0) ? a0 : (r == 1) ? a1 : (r == 2) ? a2 : a3;
        if (n + r < N) {
            h4 o;
            o.a = __float22half2_rn(make_float2(a.x, a.y));
            o.b = __float22half2_rn(make_float2(a.z, a.w));
            *reinterpret_cast<h4*>(Y + (size_t)(n + r) * 64 + h0) = o;
        }
    }
}

// T[n,c] = relu(H[n,:64]+b1) @ W2[:,c]; H fp16 in, T fp16 out (c<40, padded 64).
__global__ __launch_bounds__(256) void k_gemm2(const __half* __restrict__ H,
                                               const float* __restrict__ b1,
                                               const float* __restrict__ W2,
                                               __half* __restrict__ T, int N) {
    __shared__ float sh[64][68];
    __shared__ float sw[64][68];
    const int tid = threadIdx.x;
    const int n0 = blockIdx.x * 64;
    const bool full = (n0 + 64 <= N);
#pragma unroll
    for (int j = 0; j < 4; ++j) {
        int idx = (tid + j * 256) * 4;
        int k = idx >> 6, h = idx & 63;
        float4 v = make_float4(0.f, 0.f, 0.f, 0.f);
        if (h < 40) v = *reinterpret_cast<const float4*>(W2 + k * 40 + h);
        *reinterpret_cast<float4*>(&sw[k][h]) = v;
    }
#pragma unroll
    for (int j = 0; j < 2; ++j) {
        int idx = (tid + j * 256) * 8;
        int n = idx >> 6, k = idx & 63;
        float v[8];
        if (full || n0 + n < N) {
            h8 hv = *reinterpret_cast<const h8*>(H + (size_t)(n0 + n) * 64 + k);
            float2 f0 = __half22float2(hv.a), f1 = __half22float2(hv.b);
            float2 f2 = __half22float2(hv.c), f3 = __half22float2(hv.d);
            v[0] = f0.x; v[1] = f0.y; v[2] = f1.x; v[3] = f1.y;
            v[4] = f2.x; v[5] = f2.y; v[6] = f3.x; v[7] = f3.y;
#pragma unroll
            for (int q = 0; q < 8; ++q) v[q] = fmaxf(v[q] + b1[k + q], 0.f);
        } else {
#pragma unroll
            for (int q = 0; q < 8; ++q) v[q] = 0.f;
        }
#pragma unroll
        for (int q = 0; q < 8; ++q) sh[n][k + q] = v[q];
    }
    __syncthreads();
    const int lane = tid & 63, wid = tid >> 6;
    const int h0 = (lane & 15) * 4;
    const int nb = wid * 16 + (lane >> 4) * 4;
    float4 a0 = {0,0,0,0}, a1 = {0,0,0,0}, a2 = {0,0,0,0}, a3 = {0,0,0,0};
#pragma unroll 4
    for (int k0 = 0; k0 < 64; k0 += 4) {
        float4 x0 = *reinterpret_cast<float4*>(&sh[nb + 0][k0]);
        float4 x1 = *reinterpret_cast<float4*>(&sh[nb + 1][k0]);
        float4 x2 = *reinterpret_cast<float4*>(&sh[nb + 2][k0]);
        float4 x3 = *reinterpret_cast<float4*>(&sh[nb + 3][k0]);
        float4 w0 = *reinterpret_cast<float4*>(&sw[k0 + 0][h0]);
        float4 w1 = *reinterpret_cast<float4*>(&sw[k0 + 1][h0]);
        float4 w2 = *reinterpret_cast<float4*>(&sw[k0 + 2][h0]);
        float4 w3 = *reinterpret_cast<float4*>(&sw[k0 + 3][h0]);
        FMA4(a0, x0.x, w0); FMA4(a0, x0.y, w1); FMA4(a0, x0.z, w2); FMA4(a0, x0.w, w3);
        FMA4(a1, x1.x, w0); FMA4(a1, x1.y, w1); FMA4(a1, x1.z, w2); FMA4(a1, x1.w, w3);
        FMA4(a2, x2.x, w0); FMA4(a2, x2.y, w1); FMA4(a2, x2.z, w2); FMA4(a2, x2.w, w3);
        FMA4(a3, x3.x, w0); FMA4(a3, x3.y, w1); FMA4(a3, x3.z, w2); FMA4(a3, x3.w, w3);
    }
    if (h0 < 40) {
        int n = n0 + nb;
#pragma unroll
        for (int r = 0; r < 4; ++r) {
            float4 a = (r == 0) ? a0 : (r == 1) ? a1 : (r == 2) ? a2 : a3;
            if (n + r < N) {
                h4 o;
                o.a = __float22half2_rn(make_float2(a.x, a.y));
                o.b = __float22half2_rn(make_float2(a.z, a.w));
                *reinterpret_cast<h4*>(T + (size_t)(n + r) * 40 + h0) = o;
            }
        }
    }
}

// out[n,c] = log_softmax(T[n,:40] + b2), T fp16. One wave per node.
__global__ void k_bias_lsm(const __half* __restrict__ T, const float* __restrict__ b2,
                           float* __restrict__ Y, int N) {
    int gid = blockIdx.x * blockDim.x + threadIdx.x;
    int node = gid >> 6;
    int lane = threadIdx.x & 63;
    if (node >= N) return;
    float v = (lane < 40) ? __half2float(T[(size_t)node * 40 + lane]) + b2[lane] : -INFINITY;
    float m = v;
    for (int off = 32; off >= 1; off >>= 1) m = fmaxf(m, __shfl_xor(m, off));
    float ev = (lane < 40) ? expf(v - m) : 0.0f;
    float s = ev;
    for (int off = 32; off >= 1; off >>= 1) s += __shfl_xor(s, off);
    if (lane < 40) Y[(size_t)node * 40 + lane] = v - m - logf(s);
}

// ---------------- launch ----------------

extern "C" void kernel_launch(void* const* d_in, const int* in_sizes, int n_in,
                              void* d_out, int out_size, void* d_ws, size_t ws_size,
                              hipStream_t stream) {
    const float* x  = (const float*)d_in[0];
    const int*   ei = (const int*)d_in[1];
    const float* W1 = (const float*)d_in[2];
    const float* b1 = (const float*)d_in[3];
    const float* W2 = (const float*)d_in[4];
    const float* b2 = (const float*)d_in[5];
    float* out = (float*)d_out;

    const int H = in_sizes[3];            // 64
    const int F = in_sizes[2] / H;        // 128
    const int N = in_sizes[0] / F;        // 100000
    const int E = in_sizes[1] / 2;        // 1600000
    (void)ws_size; (void)n_in; (void)out_size;

    const int* src = ei;
    const int* dst = ei + E;
    const int NSB = div_up(N, SCH);               // node-scan blocks (49)
    const int NBK = div_up(N, BKN);               // node buckets (391)
    const int lenA = NBK * PM;                    // histA length (100096)
    const int NSA = div_up(lenA, SCH);            // histA-scan blocks (49)

    // workspace layout
    const int Npad = (N + 256) & ~255;            // covers N+1
    float* dis   = (float*)d_ws;                  // N
    int*   cnt   = (int*)(dis + Npad);            // N
    int*   rp    = cnt + Npad;                    // N+1
    int*   cur   = rp + Npad;                     // N
    int*   bsum  = cur + Npad;                    // 256 pad
    int*   bsumA = bsum + 256;                    // 256 pad (tot at +128)
    int*   histA = bsumA + 256;                   // lenA
    int*   csrc  = histA + ((lenA + 255) & ~255); // E
    __half* bufA = (__half*)(csrc + ((E + 255) & ~255));   // N*64 halfs
    __half* bufB = bufA + (size_t)N * 64;                  // N*64 halfs
    uint2* pairs = (uint2*)bufB;                  // E pairs, dead until prop1

    const int B = 256;

    // ---- CSR build (no global atomics in the placement hot path) ----
    k_zero_i32<<<div_up(N, B), B, 0, stream>>>(cnt, N);
    k_histA<<<PM, 256, 0, stream>>>(dst, cnt, histA, E, NBK);
    k_scan_part<<<NSB, 256, 0, stream>>>(cnt, bsum, N);
    k_scan_bsums<<<1, 1024, 0, stream>>>(bsum, rp + N, NSB);
    k_scan_apply<<<NSB, 256, 0, stream>>>(cnt, bsum, rp, cur, dis, N);
    k_scan_part<<<NSA, 256, 0, stream>>>(histA, bsumA, lenA);
    k_scan_bsums<<<1, 1024, 0, stream>>>(bsumA, bsumA + 128, NSA);
    k_scan_apply_plain<<<NSA, 256, 0, stream>>>(histA, bsumA, lenA);
    k_partitionA<<<PM, 256, 0, stream>>>(src, dst, histA, pairs, E, NBK);
    k_placeB<<<NBK, 256, 0, stream>>>(pairs, rp, cur, csrc, N);

    // ---- layer 1 (commuted): Y0 = X @ W1 (fp16), then 2 props at F=64 ----
    k_gemm1<<<div_up(N, 64), 256, 0, stream>>>(x, W1, bufA, N);
    k_prop_h<64><<<div_up((long long)N * 8, B), B, 0, stream>>>(rp, csrc, dis, bufA, bufB, N);
    k_prop_h<64><<<div_up((long long)N * 8, B), B, 0, stream>>>(rp, csrc, dis, bufB, bufA, N);

    // ---- layer 2 (commuted): T = relu(h + b1) @ W2 (fp16), then 2 props at F=40 ----
    k_gemm2<<<div_up(N, 64), 256, 0, stream>>>(bufA, b1, W2, bufB, N);
    k_prop_h<40><<<div_up((long long)N * 5, B), B, 0, stream>>>(rp, csrc, dis, bufB, bufA, N);
    k_prop_h<40><<<div_up((long long)N * 5, B), B, 0, stream>>>(rp, csrc, dis, bufA, bufB, N);

    // ---- epilogue: out = log_softmax(T + b2) ----
    k_bias_lsm<<<div_up((long long)N * 64, 256), 256, 0, stream>>>(bufB, b2, out, N);
}

// Round 15
// 295.440 us; speedup vs baseline: 1.3937x; 1.2459x over previous
//
#include <hip/hip_runtime.h>
#include <hip/hip_fp16.h>
#include <math.h>

__host__ __device__ static inline int div_up(long long a, long long b) { return (int)((a + b - 1) / b); }

#define SCH 2048              // scan chunk per block
#define PM 256                // edge chunks (one block per chunk in histA/partitionA)
#define BKN 256               // nodes per bucket (shift 8); buckets 256-aligned
#define CAP 8192              // LDS staging capacity (edges) in k_placeB

typedef int int4v __attribute__((ext_vector_type(4)));

struct h8 { __half2 a, b, c, d; };   // 8 halfs = 16 B
struct h4 { __half2 a, b; };         // 4 halfs = 8 B

__device__ inline int nt_load1(const int* p) {
    return __builtin_nontemporal_load(p);
}

// ---------------- CSR build (zero per-edge global atomics) ----------------

// Bucket-level LDS histogram of dst; out slice-major histA[b*PM + c].
__global__ __launch_bounds__(256) void k_histA(const int* __restrict__ dst,
                                               int* __restrict__ histA,
                                               int E, int NBK) {
    __shared__ int h[1024];               // NBK <= 1024
    const int tid = threadIdx.x, c = blockIdx.x;
    for (int i = tid; i < NBK; i += 256) h[i] = 0;
    __syncthreads();
    const int ce = (div_up(E, PM) + 3) & ~3;
    const int e0 = c * ce, e1 = min(E, e0 + ce);
    int i = e0 + tid * 4;
    for (; i + 3 < e1; i += 256 * 4) {
        int4 d = *reinterpret_cast<const int4*>(dst + i);
        atomicAdd(&h[d.x >> 8], 1);
        atomicAdd(&h[d.y >> 8], 1);
        atomicAdd(&h[d.z >> 8], 1);
        atomicAdd(&h[d.w >> 8], 1);
    }
    for (int j = i; j < e1; ++j) atomicAdd(&h[dst[j] >> 8], 1);
    __syncthreads();
    for (int b = tid; b < NBK; b += 256) histA[b * PM + c] = h[b];
}

// Scan phase 1: per-block sums of SCH-element chunks (generic length).
__global__ void k_scan_part(const int* __restrict__ a, int* __restrict__ bsum, int len) {
    __shared__ int ws[4];
    int base = blockIdx.x * SCH + threadIdx.x * 8;
    int t = 0;
#pragma unroll
    for (int j = 0; j < 8; ++j) {
        int idx = base + j;
        if (idx < len) t += a[idx];
    }
    for (int off = 32; off >= 1; off >>= 1) t += __shfl_xor(t, off);
    int lane = threadIdx.x & 63, wid = threadIdx.x >> 6;
    if (lane == 0) ws[wid] = t;
    __syncthreads();
    if (threadIdx.x == 0) bsum[blockIdx.x] = ws[0] + ws[1] + ws[2] + ws[3];
}

// Scan phase 2 (block sums, NB <= 1024) + grand total -> tot[0].
__global__ void k_scan_bsums(int* __restrict__ bsum, int* __restrict__ tot, int NB) {
    __shared__ int wsum[16];
    int tid = threadIdx.x;
    int v = (tid < NB) ? bsum[tid] : 0;
    int lane = tid & 63, wid = tid >> 6;
    int x = v;
    for (int off = 1; off < 64; off <<= 1) {
        int y = __shfl_up(x, off);
        if (lane >= off) x += y;
    }
    if (lane == 63) wsum[wid] = x;
    __syncthreads();
    if (tid < 16) {
        int s = wsum[tid];
        for (int off = 1; off < 16; off <<= 1) {
            int y = __shfl_up(s, off);
            if (tid >= off) s += y;
        }
        wsum[tid] = s;
    }
    __syncthreads();
    int woff = (wid > 0) ? wsum[wid - 1] : 0;
    int excl = woff + x - v;
    if (tid < NB) bsum[tid] = excl;
    if (tid == NB - 1) tot[0] = excl + v;
}

// Scan phase 3 (node variant): emits rp, cur, dis.
__global__ void k_scan_apply(const int* __restrict__ cnt, const int* __restrict__ bsum,
                             int* __restrict__ rp, int* __restrict__ cur,
                             float* __restrict__ dis, int N) {
    __shared__ int wsum[4];
    int tid = threadIdx.x;
    int base = blockIdx.x * SCH + tid * 8;
    int v[8];
    int t = 0;
#pragma unroll
    for (int j = 0; j < 8; ++j) {
        int idx = base + j;
        v[j] = (idx < N) ? cnt[idx] : 0;
        t += v[j];
    }
    int lane = tid & 63, wid = tid >> 6;
    int x = t;
    for (int off = 1; off < 64; off <<= 1) {
        int y = __shfl_up(x, off);
        if (lane >= off) x += y;
    }
    if (lane == 63) wsum[wid] = x;
    __syncthreads();
    int woff = 0;
    for (int w = 0; w < wid; ++w) woff += wsum[w];
    int run = bsum[blockIdx.x] + woff + (x - t);
#pragma unroll
    for (int j = 0; j < 8; ++j) {
        int idx = base + j;
        if (idx < N) {
            rp[idx] = run;
            cur[idx] = run;
            dis[idx] = rsqrtf((float)v[j] + 1.0f);
        }
        run += v[j];
    }
}

// Scan phase 3 (plain, in-place): a <- exclusive_scan(a).
__global__ void k_scan_apply_plain(int* __restrict__ a, const int* __restrict__ bsum,
                                   int len) {
    __shared__ int wsum[4];
    int tid = threadIdx.x;
    int base = blockIdx.x * SCH + tid * 8;
    int v[8];
    int t = 0;
#pragma unroll
    for (int j = 0; j < 8; ++j) {
        int idx = base + j;
        v[j] = (idx < len) ? a[idx] : 0;
        t += v[j];
    }
    int lane = tid & 63, wid = tid >> 6;
    int x = t;
    for (int off = 1; off < 64; off <<= 1) {
        int y = __shfl_up(x, off);
        if (lane >= off) x += y;
    }
    if (lane == 63) wsum[wid] = x;
    __syncthreads();
    int woff = 0;
    for (int w = 0; w < wid; ++w) woff += wsum[w];
    int run = bsum[blockIdx.x] + woff + (x - t);
#pragma unroll
    for (int j = 0; j < 8; ++j) {
        int idx = base + j;
        if (idx < len) a[idx] = run;
        run += v[j];
    }
}

// Partition edges into per-(bucket,chunk) regions via LDS cursors, packed
// uint32 = (src << 8) | (dst & 255). Valid: N < 2^24, buckets 256-aligned.
__global__ __launch_bounds__(256) void k_partitionA(
        const int* __restrict__ src, const int* __restrict__ dst,
        const int* __restrict__ pbase, unsigned* __restrict__ pairs, int E, int NBK) {
    __shared__ int curb[1024];
    const int tid = threadIdx.x, c = blockIdx.x;
    for (int b = tid; b < NBK; b += 256) curb[b] = pbase[b * PM + c];
    __syncthreads();
    const int ce = (div_up(E, PM) + 3) & ~3;
    const int e0 = c * ce, e1 = min(E, e0 + ce);
    int i = e0 + tid * 4;
    for (; i + 3 < e1; i += 256 * 4) {
        int4 d4 = *reinterpret_cast<const int4*>(dst + i);
        int4 s4 = *reinterpret_cast<const int4*>(src + i);
        int p0 = atomicAdd(&curb[d4.x >> 8], 1); pairs[p0] = ((unsigned)s4.x << 8) | (d4.x & 255);
        int p1 = atomicAdd(&curb[d4.y >> 8], 1); pairs[p1] = ((unsigned)s4.y << 8) | (d4.y & 255);
        int p2 = atomicAdd(&curb[d4.z >> 8], 1); pairs[p2] = ((unsigned)s4.z << 8) | (d4.z & 255);
        int p3 = atomicAdd(&curb[d4.w >> 8], 1); pairs[p3] = ((unsigned)s4.w << 8) | (d4.w & 255);
    }
    for (int j = i; j < e1; ++j) {
        int d = dst[j];
        int p = atomicAdd(&curb[d >> 8], 1);
        pairs[p] = ((unsigned)src[j] << 8) | (d & 255);
    }
}

// Per-node degree counts from the bucketed pairs: LDS counters, dense write.
__global__ __launch_bounds__(256) void k_cntB(
        const unsigned* __restrict__ pairs, const int* __restrict__ pbase,
        int* __restrict__ cnt, int E, int N, int NBK) {
    __shared__ int c256[BKN];
    const int b = blockIdx.x;
    const int tid = threadIdx.x;
    c256[tid] = 0;
    __syncthreads();
    const int base = pbase[b * PM];
    const int end = (b + 1 < NBK) ? pbase[(b + 1) * PM] : E;
    for (int i = base + tid; i < end; i += 256)
        atomicAdd(&c256[pairs[i] & 255], 1);
    __syncthreads();
    int n = b * BKN + tid;
    if (n < N) cnt[n] = c256[tid];
}

// Final place: one block per bucket; LDS counting-sort -> coalesced csrc write.
__global__ __launch_bounds__(256) void k_placeB(
        const unsigned* __restrict__ pairs, const int* __restrict__ rp,
        int* __restrict__ cur, int* __restrict__ csrc, int N) {
    __shared__ int curl[BKN];
    __shared__ int stage[CAP];
    const int b = blockIdx.x;
    const int n0 = b * BKN;
    const int n1 = min(N, n0 + BKN);
    const int base = rp[n0], end = rp[n1];
    const int cntb = end - base;
    const int tid = threadIdx.x;
    if (cntb <= CAP) {
        if (n0 + tid < n1) curl[tid] = rp[n0 + tid] - base;
        __syncthreads();
        for (int i = base + tid; i < end; i += 256) {
            unsigned pr = pairs[i];
            int p = atomicAdd(&curl[pr & 255], 1);
            stage[p] = (int)(pr >> 8);
        }
        __syncthreads();
        for (int i = tid; i < cntb; i += 256) csrc[base + i] = stage[i];
    } else {
        for (int i = base + tid; i < end; i += 256) {
            unsigned pr = pairs[i];
            int d = n0 + (int)(pr & 255);
            csrc[atomicAdd(&cur[d], 1)] = (int)(pr >> 8);
        }
    }
}

// ---------------- propagation (fp16 rows, fp32 accumulate) ----------------

__device__ inline void fma_h8(float* acc, float w, const h8& v) {
    float2 f0 = __half22float2(v.a), f1 = __half22float2(v.b);
    float2 f2 = __half22float2(v.c), f3 = __half22float2(v.d);
    acc[0] += w * f0.x; acc[1] += w * f0.y;
    acc[2] += w * f1.x; acc[3] += w * f1.y;
    acc[4] += w * f2.x; acc[5] += w * f2.y;
    acc[6] += w * f3.x; acc[7] += w * f3.y;
}

template<int F>  // F in halfs per row; TPE = F/8
__global__ __launch_bounds__(256) void k_prop_h(
        const int* __restrict__ rp, const int* __restrict__ csrc,
        const float* __restrict__ dis,
        const __half* __restrict__ hin, __half* __restrict__ hout, int N) {
    constexpr int TPE = F / 8;
    int t = blockIdx.x * blockDim.x + threadIdx.x;
    int n = t / TPE;
    if (n >= N) return;
    int l = t % TPE;
    float dn = dis[n];
    float acc[8];
    {
        h8 v = *reinterpret_cast<const h8*>(hin + (size_t)n * F + 8 * l);
        float wn = dn * dn;
#pragma unroll
        for (int j = 0; j < 8; ++j) acc[j] = 0.f;
        fma_h8(acc, wn, v);
    }
    int e = rp[n], end = rp[n + 1];
    for (; e + 7 < end; e += 8) {
        int s[8];
        float w[8];
        h8 v[8];
#pragma unroll
        for (int j = 0; j < 8; ++j) s[j] = nt_load1(csrc + e + j);
#pragma unroll
        for (int j = 0; j < 8; ++j) w[j] = dis[s[j]] * dn;
#pragma unroll
        for (int j = 0; j < 8; ++j)
            v[j] = *reinterpret_cast<const h8*>(hin + (size_t)s[j] * F + 8 * l);
#pragma unroll
        for (int j = 0; j < 8; ++j) fma_h8(acc, w[j], v[j]);
    }
    for (; e < end; ++e) {
        int s = nt_load1(csrc + e);
        float w = dis[s] * dn;
        h8 v = *reinterpret_cast<const h8*>(hin + (size_t)s * F + 8 * l);
        fma_h8(acc, w, v);
    }
    h8 o;
    o.a = __float22half2_rn(make_float2(acc[0], acc[1]));
    o.b = __float22half2_rn(make_float2(acc[2], acc[3]));
    o.c = __float22half2_rn(make_float2(acc[4], acc[5]));
    o.d = __float22half2_rn(make_float2(acc[6], acc[7]));
    *reinterpret_cast<h8*>(hout + (size_t)n * F + 8 * l) = o;
}

// ---------------- dense layers (register-tiled) ----------------

#define FMA4(a, s, v) { (a).x += (s) * (v).x; (a).y += (s) * (v).y; \
                        (a).z += (s) * (v).z; (a).w += (s) * (v).w; }

// Y[n,h] = X[n,:128] @ W[:,h], output fp16. Tile: 64 nodes x 64 h, 4x4/thread.
__global__ __launch_bounds__(256) void k_gemm1(const float* __restrict__ X,
                                               const float* __restrict__ W,
                                               __half* __restrict__ Y, int N) {
    __shared__ float sx[64][132];
    __shared__ float sw[128][68];
    const int tid = threadIdx.x;
    const int n0 = blockIdx.x * 64;
    const bool full = (n0 + 64 <= N);
#pragma unroll
    for (int j = 0; j < 8; ++j) {
        int idx = (tid + j * 256) * 4;
        int k = idx >> 6, h = idx & 63;
        *reinterpret_cast<float4*>(&sw[k][h]) = *reinterpret_cast<const float4*>(W + idx);
    }
#pragma unroll
    for (int j = 0; j < 8; ++j) {
        int idx = (tid + j * 256) * 4;
        int n = idx >> 7, k = idx & 127;
        float4 v = make_float4(0.f, 0.f, 0.f, 0.f);
        if (full || n0 + n < N)
            v = *reinterpret_cast<const float4*>(X + (size_t)(n0 + n) * 128 + k);
        *reinterpret_cast<float4*>(&sx[n][k]) = v;
    }
    __syncthreads();
    const int lane = tid & 63, wid = tid >> 6;
    const int h0 = (lane & 15) * 4;
    const int nb = wid * 16 + (lane >> 4) * 4;
    float4 a0 = {0,0,0,0}, a1 = {0,0,0,0}, a2 = {0,0,0,0}, a3 = {0,0,0,0};
#pragma unroll 4
    for (int k0 = 0; k0 < 128; k0 += 4) {
        float4 x0 = *reinterpret_cast<float4*>(&sx[nb + 0][k0]);
        float4 x1 = *reinterpret_cast<float4*>(&sx[nb + 1][k0]);
        float4 x2 = *reinterpret_cast<float4*>(&sx[nb + 2][k0]);
        float4 x3 = *reinterpret_cast<float4*>(&sx[nb + 3][k0]);
        float4 w0 = *reinterpret_cast<float4*>(&sw[k0 + 0][h0]);
        float4 w1 = *reinterpret_cast<float4*>(&sw[k0 + 1][h0]);
        float4 w2 = *reinterpret_cast<float4*>(&sw[k0 + 2][h0]);
        float4 w3 = *reinterpret_cast<float4*>(&sw[k0 + 3][h0]);
        FMA4(a0, x0.x, w0); FMA4(a0, x0.y, w1); FMA4(a0, x0.z, w2); FMA4(a0, x0.w, w3);
        FMA4(a1, x1.x, w0); FMA4(a1, x1.y, w1); FMA4(a1, x1.z, w2); FMA4(a1, x1.w, w3);
        FMA4(a2, x2.x, w0); FMA4(a2, x2.y, w1); FMA4(a2, x2.z, w2); FMA4(a2, x2.w, w3);
        FMA4(a3, x3.x, w0); FMA4(a3, x3.y, w1); FMA4(a3, x3.z, w2); FMA4(a3, x3.w, w3);
    }
    int n = n0 + nb;
#pragma unroll
    for (int r = 0; r < 4; ++r) {
        float4 a = (r == 0) ? a0 : (r == 1) ? a1 : (r == 2) ? a2 : a3;
        if (n + r < N) {
            h4 o;
            o.a = __float22half2_rn(make_float2(a.x, a.y));
            o.b = __float22half2_rn(make_float2(a.z, a.w));
            *reinterpret_cast<h4*>(Y + (size_t)(n + r) * 64 + h0) = o;
        }
    }
}

// T[n,c] = relu(H[n,:64]+b1) @ W2[:,c]; H fp16 in, T fp16 out (c<40, padded 64).
__global__ __launch_bounds__(256) void k_gemm2(const __half* __restrict__ H,
                                               const float* __restrict__ b1,
                                               const float* __restrict__ W2,
                                               __half* __restrict__ T, int N) {
    __shared__ float sh[64][68];
    __shared__ float sw[64][68];
    const int tid = threadIdx.x;
    const int n0 = blockIdx.x * 64;
    const bool full = (n0 + 64 <= N);
#pragma unroll
    for (int j = 0; j < 4; ++j) {
        int idx = (tid + j * 256) * 4;
        int k = idx >> 6, h = idx & 63;
        float4 v = make_float4(0.f, 0.f, 0.f, 0.f);
        if (h < 40) v = *reinterpret_cast<const float4*>(W2 + k * 40 + h);
        *reinterpret_cast<float4*>(&sw[k][h]) = v;
    }
#pragma unroll
    for (int j = 0; j < 2; ++j) {
        int idx = (tid + j * 256) * 8;
        int n = idx >> 6, k = idx & 63;
        float v[8];
        if (full || n0 + n < N) {
            h8 hv = *reinterpret_cast<const h8*>(H + (size_t)(n0 + n) * 64 + k);
            float2 f0 = __half22float2(hv.a), f1 = __half22float2(hv.b);
            float2 f2 = __half22float2(hv.c), f3 = __half22float2(hv.d);
            v[0] = f0.x; v[1] = f0.y; v[2] = f1.x; v[3] = f1.y;
            v[4] = f2.x; v[5] = f2.y; v[6] = f3.x; v[7] = f3.y;
#pragma unroll
            for (int q = 0; q < 8; ++q) v[q] = fmaxf(v[q] + b1[k + q], 0.f);
        } else {
#pragma unroll
            for (int q = 0; q < 8; ++q) v[q] = 0.f;
        }
#pragma unroll
        for (int q = 0; q < 8; ++q) sh[n][k + q] = v[q];
    }
    __syncthreads();
    const int lane = tid & 63, wid = tid >> 6;
    const int h0 = (lane & 15) * 4;
    const int nb = wid * 16 + (lane >> 4) * 4;
    float4 a0 = {0,0,0,0}, a1 = {0,0,0,0}, a2 = {0,0,0,0}, a3 = {0,0,0,0};
#pragma unroll 4
    for (int k0 = 0; k0 < 64; k0 += 4) {
        float4 x0 = *reinterpret_cast<float4*>(&sh[nb + 0][k0]);
        float4 x1 = *reinterpret_cast<float4*>(&sh[nb + 1][k0]);
        float4 x2 = *reinterpret_cast<float4*>(&sh[nb + 2][k0]);
        float4 x3 = *reinterpret_cast<float4*>(&sh[nb + 3][k0]);
        float4 w0 = *reinterpret_cast<float4*>(&sw[k0 + 0][h0]);
        float4 w1 = *reinterpret_cast<float4*>(&sw[k0 + 1][h0]);
        float4 w2 = *reinterpret_cast<float4*>(&sw[k0 + 2][h0]);
        float4 w3 = *reinterpret_cast<float4*>(&sw[k0 + 3][h0]);
        FMA4(a0, x0.x, w0); FMA4(a0, x0.y, w1); FMA4(a0, x0.z, w2); FMA4(a0, x0.w, w3);
        FMA4(a1, x1.x, w0); FMA4(a1, x1.y, w1); FMA4(a1, x1.z, w2); FMA4(a1, x1.w, w3);
        FMA4(a2, x2.x, w0); FMA4(a2, x2.y, w1); FMA4(a2, x2.z, w2); FMA4(a2, x2.w, w3);
        FMA4(a3, x3.x, w0); FMA4(a3, x3.y, w1); FMA4(a3, x3.z, w2); FMA4(a3, x3.w, w3);
    }
    if (h0 < 40) {
        int n = n0 + nb;
#pragma unroll
        for (int r = 0; r < 4; ++r) {
            float4 a = (r == 0) ? a0 : (r == 1) ? a1 : (r == 2) ? a2 : a3;
            if (n + r < N) {
                h4 o;
                o.a = __float22half2_rn(make_float2(a.x, a.y));
                o.b = __float22half2_rn(make_float2(a.z, a.w));
                *reinterpret_cast<h4*>(T + (size_t)(n + r) * 40 + h0) = o;
            }
        }
    }
}

// out[n,c] = log_softmax(T[n,:40] + b2), T fp16. One wave per node.
__global__ void k_bias_lsm(const __half* __restrict__ T, const float* __restrict__ b2,
                           float* __restrict__ Y, int N) {
    int gid = blockIdx.x * blockDim.x + threadIdx.x;
    int node = gid >> 6;
    int lane = threadIdx.x & 63;
    if (node >= N) return;
    float v = (lane < 40) ? __half2float(T[(size_t)node * 40 + lane]) + b2[lane] : -INFINITY;
    float m = v;
    for (int off = 32; off >= 1; off >>= 1) m = fmaxf(m, __shfl_xor(m, off));
    float ev = (lane < 40) ? expf(v - m) : 0.0f;
    float s = ev;
    for (int off = 32; off >= 1; off >>= 1) s += __shfl_xor(s, off);
    if (lane < 40) Y[(size_t)node * 40 + lane] = v - m - logf(s);
}

// ---------------- launch ----------------

extern "C" void kernel_launch(void* const* d_in, const int* in_sizes, int n_in,
                              void* d_out, int out_size, void* d_ws, size_t ws_size,
                              hipStream_t stream) {
    const float* x  = (const float*)d_in[0];
    const int*   ei = (const int*)d_in[1];
    const float* W1 = (const float*)d_in[2];
    const float* b1 = (const float*)d_in[3];
    const float* W2 = (const float*)d_in[4];
    const float* b2 = (const float*)d_in[5];
    float* out = (float*)d_out;

    const int H = in_sizes[3];            // 64
    const int F = in_sizes[2] / H;        // 128
    const int N = in_sizes[0] / F;        // 100000
    const int E = in_sizes[1] / 2;        // 1600000
    (void)ws_size; (void)n_in; (void)out_size;

    const int* src = ei;
    const int* dst = ei + E;
    const int NSB = div_up(N, SCH);               // node-scan blocks (49)
    const int NBK = div_up(N, BKN);               // node buckets (391)
    const int lenA = NBK * PM;                    // histA length (100096)
    const int NSA = div_up(lenA, SCH);            // histA-scan blocks (49)

    // workspace layout
    const int Npad = (N + 256) & ~255;            // covers N+1
    float* dis   = (float*)d_ws;                  // N
    int*   cnt   = (int*)(dis + Npad);            // N
    int*   rp    = cnt + Npad;                    // N+1
    int*   cur   = rp + Npad;                     // N
    int*   bsum  = cur + Npad;                    // 256 pad
    int*   bsumA = bsum + 256;                    // 256 pad (tot at +128)
    int*   histA = bsumA + 256;                   // lenA
    int*   csrc  = histA + ((lenA + 255) & ~255); // E
    __half* bufA = (__half*)(csrc + ((E + 255) & ~255));   // N*64 halfs
    __half* bufB = bufA + (size_t)N * 64;                  // N*64 halfs
    unsigned* pairs = (unsigned*)bufB;            // E u32, dead until prop1

    const int B = 256;

    // ---- CSR build (no per-edge global atomics anywhere) ----
    k_histA<<<PM, 256, 0, stream>>>(dst, histA, E, NBK);
    k_scan_part<<<NSA, 256, 0, stream>>>(histA, bsumA, lenA);
    k_scan_bsums<<<1, 1024, 0, stream>>>(bsumA, bsumA + 128, NSA);
    k_scan_apply_plain<<<NSA, 256, 0, stream>>>(histA, bsumA, lenA);
    k_partitionA<<<PM, 256, 0, stream>>>(src, dst, histA, pairs, E, NBK);
    k_cntB<<<NBK, 256, 0, stream>>>(pairs, histA, cnt, E, N, NBK);
    k_scan_part<<<NSB, 256, 0, stream>>>(cnt, bsum, N);
    k_scan_bsums<<<1, 1024, 0, stream>>>(bsum, rp + N, NSB);
    k_scan_apply<<<NSB, 256, 0, stream>>>(cnt, bsum, rp, cur, dis, N);
    k_placeB<<<NBK, 256, 0, stream>>>(pairs, rp, cur, csrc, N);

    // ---- layer 1 (commuted): Y0 = X @ W1 (fp16), then 2 props at F=64 ----
    k_gemm1<<<div_up(N, 64), 256, 0, stream>>>(x, W1, bufA, N);
    k_prop_h<64><<<div_up((long long)N * 8, B), B, 0, stream>>>(rp, csrc, dis, bufA, bufB, N);
    k_prop_h<64><<<div_up((long long)N * 8, B), B, 0, stream>>>(rp, csrc, dis, bufB, bufA, N);

    // ---- layer 2 (commuted): T = relu(h + b1) @ W2 (fp16), then 2 props at F=40 ----
    k_gemm2<<<div_up(N, 64), 256, 0, stream>>>(bufA, b1, W2, bufB, N);
    k_prop_h<40><<<div_up((long long)N * 5, B), B, 0, stream>>>(rp, csrc, dis, bufB, bufA, N);
    k_prop_h<40><<<div_up((long long)N * 5, B), B, 0, stream>>>(rp, csrc, dis, bufA, bufB, N);

    // ---- epilogue: out = log_softmax(T + b2) ----
    k_bias_lsm<<<div_up((long long)N * 64, 256), 256, 0, stream>>>(bufB, b2, out, N);
}

// Round 16
// 280.982 us; speedup vs baseline: 1.4654x; 1.0515x over previous
//
#include <hip/hip_runtime.h>
#include <hip/hip_fp16.h>
#include <math.h>

__host__ __device__ static inline int div_up(long long a, long long b) { return (int)((a + b - 1) / b); }

#define SCH 2048              // scan chunk per block
#define PM 256                // edge chunks (one block per chunk in histA/partitionA)
#define BKN 256               // nodes per bucket (shift 8); buckets 256-aligned
#define CAP 8192              // LDS staging capacity (edges) in k_placeB
#define PROPG 2048            // persistent blocks for propagation

struct h8 { __half2 a, b, c, d; };   // 8 halfs = 16 B
struct h4 { __half2 a, b; };         // 4 halfs = 8 B

__device__ inline int nt_load1(const int* p) {
    return __builtin_nontemporal_load(p);
}

// ---------------- CSR build (zero per-edge global atomics) ----------------

// Bucket-level LDS histogram of dst; out slice-major histA[b*PM + c].
__global__ __launch_bounds__(256) void k_histA(const int* __restrict__ dst,
                                               int* __restrict__ histA,
                                               int E, int NBK) {
    __shared__ int h[1024];               // NBK <= 1024
    const int tid = threadIdx.x, c = blockIdx.x;
    for (int i = tid; i < NBK; i += 256) h[i] = 0;
    __syncthreads();
    const int ce = (div_up(E, PM) + 3) & ~3;
    const int e0 = c * ce, e1 = min(E, e0 + ce);
    int i = e0 + tid * 4;
    for (; i + 3 < e1; i += 256 * 4) {
        int4 d = *reinterpret_cast<const int4*>(dst + i);
        atomicAdd(&h[d.x >> 8], 1);
        atomicAdd(&h[d.y >> 8], 1);
        atomicAdd(&h[d.z >> 8], 1);
        atomicAdd(&h[d.w >> 8], 1);
    }
    for (int j = i; j < e1; ++j) atomicAdd(&h[dst[j] >> 8], 1);
    __syncthreads();
    for (int b = tid; b < NBK; b += 256) histA[b * PM + c] = h[b];
}

// Scan phase 1: per-block sums of SCH-element chunks (generic length).
__global__ void k_scan_part(const int* __restrict__ a, int* __restrict__ bsum, int len) {
    __shared__ int ws[4];
    int base = blockIdx.x * SCH + threadIdx.x * 8;
    int t = 0;
#pragma unroll
    for (int j = 0; j < 8; ++j) {
        int idx = base + j;
        if (idx < len) t += a[idx];
    }
    for (int off = 32; off >= 1; off >>= 1) t += __shfl_xor(t, off);
    int lane = threadIdx.x & 63, wid = threadIdx.x >> 6;
    if (lane == 0) ws[wid] = t;
    __syncthreads();
    if (threadIdx.x == 0) bsum[blockIdx.x] = ws[0] + ws[1] + ws[2] + ws[3];
}

// Scan phase 2 (block sums, NB <= 1024) + grand total -> tot[0].
__global__ void k_scan_bsums(int* __restrict__ bsum, int* __restrict__ tot, int NB) {
    __shared__ int wsum[16];
    int tid = threadIdx.x;
    int v = (tid < NB) ? bsum[tid] : 0;
    int lane = tid & 63, wid = tid >> 6;
    int x = v;
    for (int off = 1; off < 64; off <<= 1) {
        int y = __shfl_up(x, off);
        if (lane >= off) x += y;
    }
    if (lane == 63) wsum[wid] = x;
    __syncthreads();
    if (tid < 16) {
        int s = wsum[tid];
        for (int off = 1; off < 16; off <<= 1) {
            int y = __shfl_up(s, off);
            if (tid >= off) s += y;
        }
        wsum[tid] = s;
    }
    __syncthreads();
    int woff = (wid > 0) ? wsum[wid - 1] : 0;
    int excl = woff + x - v;
    if (tid < NB) bsum[tid] = excl;
    if (tid == NB - 1) tot[0] = excl + v;
}

// Scan phase 3 (node variant): emits rp, cur, dis, inv.
__global__ void k_scan_apply(const int* __restrict__ cnt, const int* __restrict__ bsum,
                             int* __restrict__ rp, int* __restrict__ cur,
                             float* __restrict__ dis, float* __restrict__ inv, int N) {
    __shared__ int wsum[4];
    int tid = threadIdx.x;
    int base = blockIdx.x * SCH + tid * 8;
    int v[8];
    int t = 0;
#pragma unroll
    for (int j = 0; j < 8; ++j) {
        int idx = base + j;
        v[j] = (idx < N) ? cnt[idx] : 0;
        t += v[j];
    }
    int lane = tid & 63, wid = tid >> 6;
    int x = t;
    for (int off = 1; off < 64; off <<= 1) {
        int y = __shfl_up(x, off);
        if (lane >= off) x += y;
    }
    if (lane == 63) wsum[wid] = x;
    __syncthreads();
    int woff = 0;
    for (int w = 0; w < wid; ++w) woff += wsum[w];
    int run = bsum[blockIdx.x] + woff + (x - t);
#pragma unroll
    for (int j = 0; j < 8; ++j) {
        int idx = base + j;
        if (idx < N) {
            rp[idx] = run;
            cur[idx] = run;
            float dg = (float)v[j] + 1.0f;
            dis[idx] = rsqrtf(dg);
            inv[idx] = sqrtf(dg);
        }
        run += v[j];
    }
}

// Scan phase 3 (plain, in-place): a <- exclusive_scan(a).
__global__ void k_scan_apply_plain(int* __restrict__ a, const int* __restrict__ bsum,
                                   int len) {
    __shared__ int wsum[4];
    int tid = threadIdx.x;
    int base = blockIdx.x * SCH + tid * 8;
    int v[8];
    int t = 0;
#pragma unroll
    for (int j = 0; j < 8; ++j) {
        int idx = base + j;
        v[j] = (idx < len) ? a[idx] : 0;
        t += v[j];
    }
    int lane = tid & 63, wid = tid >> 6;
    int x = t;
    for (int off = 1; off < 64; off <<= 1) {
        int y = __shfl_up(x, off);
        if (lane >= off) x += y;
    }
    if (lane == 63) wsum[wid] = x;
    __syncthreads();
    int woff = 0;
    for (int w = 0; w < wid; ++w) woff += wsum[w];
    int run = bsum[blockIdx.x] + woff + (x - t);
#pragma unroll
    for (int j = 0; j < 8; ++j) {
        int idx = base + j;
        if (idx < len) a[idx] = run;
        run += v[j];
    }
}

// Partition edges into per-(bucket,chunk) regions via LDS cursors, packed
// uint32 = (src << 8) | (dst & 255). Valid: N < 2^24, buckets 256-aligned.
__global__ __launch_bounds__(256) void k_partitionA(
        const int* __restrict__ src, const int* __restrict__ dst,
        const int* __restrict__ pbase, unsigned* __restrict__ pairs, int E, int NBK) {
    __shared__ int curb[1024];
    const int tid = threadIdx.x, c = blockIdx.x;
    for (int b = tid; b < NBK; b += 256) curb[b] = pbase[b * PM + c];
    __syncthreads();
    const int ce = (div_up(E, PM) + 3) & ~3;
    const int e0 = c * ce, e1 = min(E, e0 + ce);
    int i = e0 + tid * 4;
    for (; i + 3 < e1; i += 256 * 4) {
        int4 d4 = *reinterpret_cast<const int4*>(dst + i);
        int4 s4 = *reinterpret_cast<const int4*>(src + i);
        int p0 = atomicAdd(&curb[d4.x >> 8], 1); pairs[p0] = ((unsigned)s4.x << 8) | (d4.x & 255);
        int p1 = atomicAdd(&curb[d4.y >> 8], 1); pairs[p1] = ((unsigned)s4.y << 8) | (d4.y & 255);
        int p2 = atomicAdd(&curb[d4.z >> 8], 1); pairs[p2] = ((unsigned)s4.z << 8) | (d4.z & 255);
        int p3 = atomicAdd(&curb[d4.w >> 8], 1); pairs[p3] = ((unsigned)s4.w << 8) | (d4.w & 255);
    }
    for (int j = i; j < e1; ++j) {
        int d = dst[j];
        int p = atomicAdd(&curb[d >> 8], 1);
        pairs[p] = ((unsigned)src[j] << 8) | (d & 255);
    }
}

// Per-node degree counts from the bucketed pairs: LDS counters, dense write.
__global__ __launch_bounds__(256) void k_cntB(
        const unsigned* __restrict__ pairs, const int* __restrict__ pbase,
        int* __restrict__ cnt, int E, int N, int NBK) {
    __shared__ int c256[BKN];
    const int b = blockIdx.x;
    const int tid = threadIdx.x;
    c256[tid] = 0;
    __syncthreads();
    const int base = pbase[b * PM];
    const int end = (b + 1 < NBK) ? pbase[(b + 1) * PM] : E;
    for (int i = base + tid; i < end; i += 256)
        atomicAdd(&c256[pairs[i] & 255], 1);
    __syncthreads();
    int n = b * BKN + tid;
    if (n < N) cnt[n] = c256[tid];
}

// Final place: one block per bucket; LDS counting-sort -> coalesced csrc write.
__global__ __launch_bounds__(256) void k_placeB(
        const unsigned* __restrict__ pairs, const int* __restrict__ rp,
        int* __restrict__ cur, int* __restrict__ csrc, int N) {
    __shared__ int curl[BKN];
    __shared__ int stage[CAP];
    const int b = blockIdx.x;
    const int n0 = b * BKN;
    const int n1 = min(N, n0 + BKN);
    const int base = rp[n0], end = rp[n1];
    const int cntb = end - base;
    const int tid = threadIdx.x;
    if (cntb <= CAP) {
        if (n0 + tid < n1) curl[tid] = rp[n0 + tid] - base;
        __syncthreads();
        for (int i = base + tid; i < end; i += 256) {
            unsigned pr = pairs[i];
            int p = atomicAdd(&curl[pr & 255], 1);
            stage[p] = (int)(pr >> 8);
        }
        __syncthreads();
        for (int i = tid; i < cntb; i += 256) csrc[base + i] = stage[i];
    } else {
        for (int i = base + tid; i < end; i += 256) {
            unsigned pr = pairs[i];
            int d = n0 + (int)(pr & 255);
            csrc[atomicAdd(&cur[d], 1)] = (int)(pr >> 8);
        }
    }
}

// ---------------- propagation (scaled form: buffers hold h' = dis*h) ----------------
// h_out'[n] = dis[n]^2 * ( h'[n] + sum_{s in N(n)} h'[s] )  -- no per-edge weights.

__device__ inline void add_h8(float* acc, const h8& v) {
    float2 f0 = __half22float2(v.a), f1 = __half22float2(v.b);
    float2 f2 = __half22float2(v.c), f3 = __half22float2(v.d);
    acc[0] += f0.x; acc[1] += f0.y;
    acc[2] += f1.x; acc[3] += f1.y;
    acc[4] += f2.x; acc[5] += f2.y;
    acc[6] += f3.x; acc[7] += f3.y;
}

template<int F>  // F in halfs per row; TPE = F/8
__global__ __launch_bounds__(256) void k_prop_h(
        const int* __restrict__ rp, const int* __restrict__ csrc,
        const float* __restrict__ dis,
        const __half* __restrict__ hin, __half* __restrict__ hout, int N) {
    constexpr int TPE = F / 8;
    const long long total = (long long)N * TPE;
    const long long stride = (long long)gridDim.x * 256;
    for (long long t = (long long)blockIdx.x * 256 + threadIdx.x; t < total; t += stride) {
        int n = (int)(t / TPE);
        int l = (int)(t % TPE);
        float acc[8];
        {
            h8 v = *reinterpret_cast<const h8*>(hin + (size_t)n * F + 8 * l);
#pragma unroll
            for (int j = 0; j < 8; ++j) acc[j] = 0.f;
            add_h8(acc, v);
        }
        int e = rp[n], end = rp[n + 1];
        for (; e + 7 < end; e += 8) {
            int s[8];
            h8 v[8];
#pragma unroll
            for (int j = 0; j < 8; ++j) s[j] = nt_load1(csrc + e + j);
#pragma unroll
            for (int j = 0; j < 8; ++j)
                v[j] = *reinterpret_cast<const h8*>(hin + (size_t)s[j] * F + 8 * l);
#pragma unroll
            for (int j = 0; j < 8; ++j) add_h8(acc, v[j]);
        }
        for (; e < end; ++e) {
            int s = nt_load1(csrc + e);
            h8 v = *reinterpret_cast<const h8*>(hin + (size_t)s * F + 8 * l);
            add_h8(acc, v);
        }
        float dn = dis[n];
        float d2 = dn * dn;
        h8 o;
        o.a = __float22half2_rn(make_float2(acc[0] * d2, acc[1] * d2));
        o.b = __float22half2_rn(make_float2(acc[2] * d2, acc[3] * d2));
        o.c = __float22half2_rn(make_float2(acc[4] * d2, acc[5] * d2));
        o.d = __float22half2_rn(make_float2(acc[6] * d2, acc[7] * d2));
        *reinterpret_cast<h8*>(hout + (size_t)n * F + 8 * l) = o;
    }
}

// ---------------- dense layers (register-tiled) ----------------

#define FMA4(a, s, v) { (a).x += (s) * (v).x; (a).y += (s) * (v).y; \
                        (a).z += (s) * (v).z; (a).w += (s) * (v).w; }

// Y'[n,h] = dis[n] * (X[n,:128] @ W[:,h]), output fp16 (scaled form).
__global__ __launch_bounds__(256) void k_gemm1(const float* __restrict__ X,
                                               const float* __restrict__ W,
                                               const float* __restrict__ dis,
                                               __half* __restrict__ Y, int N) {
    __shared__ float sx[64][132];
    __shared__ float sw[128][68];
    const int tid = threadIdx.x;
    const int n0 = blockIdx.x * 64;
    const bool full = (n0 + 64 <= N);
#pragma unroll
    for (int j = 0; j < 8; ++j) {
        int idx = (tid + j * 256) * 4;
        int k = idx >> 6, h = idx & 63;
        *reinterpret_cast<float4*>(&sw[k][h]) = *reinterpret_cast<const float4*>(W + idx);
    }
#pragma unroll
    for (int j = 0; j < 8; ++j) {
        int idx = (tid + j * 256) * 4;
        int n = idx >> 7, k = idx & 127;
        float4 v = make_float4(0.f, 0.f, 0.f, 0.f);
        if (full || n0 + n < N)
            v = *reinterpret_cast<const float4*>(X + (size_t)(n0 + n) * 128 + k);
        *reinterpret_cast<float4*>(&sx[n][k]) = v;
    }
    __syncthreads();
    const int lane = tid & 63, wid = tid >> 6;
    const int h0 = (lane & 15) * 4;
    const int nb = wid * 16 + (lane >> 4) * 4;
    float4 a0 = {0,0,0,0}, a1 = {0,0,0,0}, a2 = {0,0,0,0}, a3 = {0,0,0,0};
#pragma unroll 4
    for (int k0 = 0; k0 < 128; k0 += 4) {
        float4 x0 = *reinterpret_cast<float4*>(&sx[nb + 0][k0]);
        float4 x1 = *reinterpret_cast<float4*>(&sx[nb + 1][k0]);
        float4 x2 = *reinterpret_cast<float4*>(&sx[nb + 2][k0]);
        float4 x3 = *reinterpret_cast<float4*>(&sx[nb + 3][k0]);
        float4 w0 = *reinterpret_cast<float4*>(&sw[k0 + 0][h0]);
        float4 w1 = *reinterpret_cast<float4*>(&sw[k0 + 1][h0]);
        float4 w2 = *reinterpret_cast<float4*>(&sw[k0 + 2][h0]);
        float4 w3 = *reinterpret_cast<float4*>(&sw[k0 + 3][h0]);
        FMA4(a0, x0.x, w0); FMA4(a0, x0.y, w1); FMA4(a0, x0.z, w2); FMA4(a0, x0.w, w3);
        FMA4(a1, x1.x, w0); FMA4(a1, x1.y, w1); FMA4(a1, x1.z, w2); FMA4(a1, x1.w, w3);
        FMA4(a2, x2.x, w0); FMA4(a2, x2.y, w1); FMA4(a2, x2.z, w2); FMA4(a2, x2.w, w3);
        FMA4(a3, x3.x, w0); FMA4(a3, x3.y, w1); FMA4(a3, x3.z, w2); FMA4(a3, x3.w, w3);
    }
    int n = n0 + nb;
#pragma unroll
    for (int r = 0; r < 4; ++r) {
        float4 a = (r == 0) ? a0 : (r == 1) ? a1 : (r == 2) ? a2 : a3;
        if (n + r < N) {
            float sc = dis[n + r];
            h4 o;
            o.a = __float22half2_rn(make_float2(a.x * sc, a.y * sc));
            o.b = __float22half2_rn(make_float2(a.z * sc, a.w * sc));
            *reinterpret_cast<h4*>(Y + (size_t)(n + r) * 64 + h0) = o;
        }
    }
}

// T'[n,c] = dis[n] * ( relu(inv[n]*H'[n,:64]+b1) @ W2[:,c] ); scaled fp16 in/out.
__global__ __launch_bounds__(256) void k_gemm2(const __half* __restrict__ H,
                                               const float* __restrict__ b1,
                                               const float* __restrict__ W2,
                                               const float* __restrict__ dis,
                                               const float* __restrict__ inv,
                                               __half* __restrict__ T, int N) {
    __shared__ float sh[64][68];
    __shared__ float sw[64][68];
    const int tid = threadIdx.x;
    const int n0 = blockIdx.x * 64;
    const bool full = (n0 + 64 <= N);
#pragma unroll
    for (int j = 0; j < 4; ++j) {
        int idx = (tid + j * 256) * 4;
        int k = idx >> 6, h = idx & 63;
        float4 v = make_float4(0.f, 0.f, 0.f, 0.f);
        if (h < 40) v = *reinterpret_cast<const float4*>(W2 + k * 40 + h);
        *reinterpret_cast<float4*>(&sw[k][h]) = v;
    }
#pragma unroll
    for (int j = 0; j < 2; ++j) {
        int idx = (tid + j * 256) * 8;
        int n = idx >> 6, k = idx & 63;
        float v[8];
        if (full || n0 + n < N) {
            float iv = inv[n0 + n];
            h8 hv = *reinterpret_cast<const h8*>(H + (size_t)(n0 + n) * 64 + k);
            float2 f0 = __half22float2(hv.a), f1 = __half22float2(hv.b);
            float2 f2 = __half22float2(hv.c), f3 = __half22float2(hv.d);
            v[0] = f0.x; v[1] = f0.y; v[2] = f1.x; v[3] = f1.y;
            v[4] = f2.x; v[5] = f2.y; v[6] = f3.x; v[7] = f3.y;
#pragma unroll
            for (int q = 0; q < 8; ++q) v[q] = fmaxf(v[q] * iv + b1[k + q], 0.f);
        } else {
#pragma unroll
            for (int q = 0; q < 8; ++q) v[q] = 0.f;
        }
#pragma unroll
        for (int q = 0; q < 8; ++q) sh[n][k + q] = v[q];
    }
    __syncthreads();
    const int lane = tid & 63, wid = tid >> 6;
    const int h0 = (lane & 15) * 4;
    const int nb = wid * 16 + (lane >> 4) * 4;
    float4 a0 = {0,0,0,0}, a1 = {0,0,0,0}, a2 = {0,0,0,0}, a3 = {0,0,0,0};
#pragma unroll 4
    for (int k0 = 0; k0 < 64; k0 += 4) {
        float4 x0 = *reinterpret_cast<float4*>(&sh[nb + 0][k0]);
        float4 x1 = *reinterpret_cast<float4*>(&sh[nb + 1][k0]);
        float4 x2 = *reinterpret_cast<float4*>(&sh[nb + 2][k0]);
        float4 x3 = *reinterpret_cast<float4*>(&sh[nb + 3][k0]);
        float4 w0 = *reinterpret_cast<float4*>(&sw[k0 + 0][h0]);
        float4 w1 = *reinterpret_cast<float4*>(&sw[k0 + 1][h0]);
        float4 w2 = *reinterpret_cast<float4*>(&sw[k0 + 2][h0]);
        float4 w3 = *reinterpret_cast<float4*>(&sw[k0 + 3][h0]);
        FMA4(a0, x0.x, w0); FMA4(a0, x0.y, w1); FMA4(a0, x0.z, w2); FMA4(a0, x0.w, w3);
        FMA4(a1, x1.x, w0); FMA4(a1, x1.y, w1); FMA4(a1, x1.z, w2); FMA4(a1, x1.w, w3);
        FMA4(a2, x2.x, w0); FMA4(a2, x2.y, w1); FMA4(a2, x2.z, w2); FMA4(a2, x2.w, w3);
        FMA4(a3, x3.x, w0); FMA4(a3, x3.y, w1); FMA4(a3, x3.z, w2); FMA4(a3, x3.w, w3);
    }
    if (h0 < 40) {
        int n = n0 + nb;
#pragma unroll
        for (int r = 0; r < 4; ++r) {
            float4 a = (r == 0) ? a0 : (r == 1) ? a1 : (r == 2) ? a2 : a3;
            if (n + r < N) {
                float sc = dis[n + r];
                h4 o;
                o.a = __float22half2_rn(make_float2(a.x * sc, a.y * sc));
                o.b = __float22half2_rn(make_float2(a.z * sc, a.w * sc));
                *reinterpret_cast<h4*>(T + (size_t)(n + r) * 40 + h0) = o;
            }
        }
    }
}

// out[n,c] = log_softmax(inv[n]*T'[n,:40] + b2), T' scaled fp16. One wave/node.
__global__ void k_bias_lsm(const __half* __restrict__ T, const float* __restrict__ b2,
                           const float* __restrict__ inv, float* __restrict__ Y, int N) {
    int gid = blockIdx.x * blockDim.x + threadIdx.x;
    int node = gid >> 6;
    int lane = threadIdx.x & 63;
    if (node >= N) return;
    float iv = inv[node];
    float v = (lane < 40) ? __half2float(T[(size_t)node * 40 + lane]) * iv + b2[lane]
                          : -INFINITY;
    float m = v;
    for (int off = 32; off >= 1; off >>= 1) m = fmaxf(m, __shfl_xor(m, off));
    float ev = (lane < 40) ? expf(v - m) : 0.0f;
    float s = ev;
    for (int off = 32; off >= 1; off >>= 1) s += __shfl_xor(s, off);
    if (lane < 40) Y[(size_t)node * 40 + lane] = v - m - logf(s);
}

// ---------------- launch ----------------

extern "C" void kernel_launch(void* const* d_in, const int* in_sizes, int n_in,
                              void* d_out, int out_size, void* d_ws, size_t ws_size,
                              hipStream_t stream) {
    const float* x  = (const float*)d_in[0];
    const int*   ei = (const int*)d_in[1];
    const float* W1 = (const float*)d_in[2];
    const float* b1 = (const float*)d_in[3];
    const float* W2 = (const float*)d_in[4];
    const float* b2 = (const float*)d_in[5];
    float* out = (float*)d_out;

    const int H = in_sizes[3];            // 64
    const int F = in_sizes[2] / H;        // 128
    const int N = in_sizes[0] / F;        // 100000
    const int E = in_sizes[1] / 2;        // 1600000
    (void)ws_size; (void)n_in; (void)out_size;

    const int* src = ei;
    const int* dst = ei + E;
    const int NSB = div_up(N, SCH);               // node-scan blocks (49)
    const int NBK = div_up(N, BKN);               // node buckets (391)
    const int lenA = NBK * PM;                    // histA length (100096)
    const int NSA = div_up(lenA, SCH);            // histA-scan blocks (49)

    // workspace layout
    const int Npad = (N + 256) & ~255;            // covers N+1
    float* dis   = (float*)d_ws;                  // N
    float* inv   = dis + Npad;                    // N
    int*   cnt   = (int*)(inv + Npad);            // N
    int*   rp    = cnt + Npad;                    // N+1
    int*   cur   = rp + Npad;                     // N
    int*   bsum  = cur + Npad;                    // 256 pad
    int*   bsumA = bsum + 256;                    // 256 pad (tot at +128)
    int*   histA = bsumA + 256;                   // lenA
    int*   csrc  = histA + ((lenA + 255) & ~255); // E
    __half* bufA = (__half*)(csrc + ((E + 255) & ~255));   // N*64 halfs
    __half* bufB = bufA + (size_t)N * 64;                  // N*64 halfs
    unsigned* pairs = (unsigned*)bufB;            // E u32, dead until prop1

    const int B = 256;

    // ---- CSR build (no per-edge global atomics anywhere) ----
    k_histA<<<PM, 256, 0, stream>>>(dst, histA, E, NBK);
    k_scan_part<<<NSA, 256, 0, stream>>>(histA, bsumA, lenA);
    k_scan_bsums<<<1, 1024, 0, stream>>>(bsumA, bsumA + 128, NSA);
    k_scan_apply_plain<<<NSA, 256, 0, stream>>>(histA, bsumA, lenA);
    k_partitionA<<<PM, 256, 0, stream>>>(src, dst, histA, pairs, E, NBK);
    k_cntB<<<NBK, 256, 0, stream>>>(pairs, histA, cnt, E, N, NBK);
    k_scan_part<<<NSB, 256, 0, stream>>>(cnt, bsum, N);
    k_scan_bsums<<<1, 1024, 0, stream>>>(bsum, rp + N, NSB);
    k_scan_apply<<<NSB, 256, 0, stream>>>(cnt, bsum, rp, cur, dis, inv, N);
    k_placeB<<<NBK, 256, 0, stream>>>(pairs, rp, cur, csrc, N);

    // ---- layer 1 (commuted, scaled form): Y' = dis*(X@W1), 2 props at F=64 ----
    k_gemm1<<<div_up(N, 64), 256, 0, stream>>>(x, W1, dis, bufA, N);
    k_prop_h<64><<<PROPG, B, 0, stream>>>(rp, csrc, dis, bufA, bufB, N);
    k_prop_h<64><<<PROPG, B, 0, stream>>>(rp, csrc, dis, bufB, bufA, N);

    // ---- layer 2 (commuted, scaled form): T' = dis*(relu(inv*h'+b1)@W2), 2 props F=40 ----
    k_gemm2<<<div_up(N, 64), 256, 0, stream>>>(bufA, b1, W2, dis, inv, bufB, N);
    k_prop_h<40><<<PROPG, B, 0, stream>>>(rp, csrc, dis, bufB, bufA, N);
    k_prop_h<40><<<PROPG, B, 0, stream>>>(rp, csrc, dis, bufA, bufB, N);

    // ---- epilogue: out = log_softmax(inv*T' + b2) ----
    k_bias_lsm<<<div_up((long long)N * 64, 256), 256, 0, stream>>>(bufB, b2, inv, out, N);
}